// Round 1
// baseline (571.371 us; speedup 1.0000x reference)
//
#include <hip/hip_runtime.h>
#include <math.h>

#define FIN 128
#define H 64
#define FOUT 2
#define NEG_SLOPE 0.2f
#define EPS 1e-16f

__device__ __forceinline__ float waveSum(float v){
  #pragma unroll
  for(int o=1;o<64;o<<=1) v += __shfl_xor(v,o);
  return v;
}
__device__ __forceinline__ float waveMax(float v){
  #pragma unroll
  for(int o=1;o<64;o<<=1) v = fmaxf(v, __shfl_xor(v,o));
  return v;
}

// K0: zero int buffer
__global__ void k_zero_int(int* __restrict__ a, int n){
  int i = blockIdx.x*blockDim.x + threadIdx.x;
  int stride = gridDim.x*blockDim.x;
  for(; i<n; i+=stride) a[i]=0;
}

// K1: xl = x@Wl, xr = x@Wr ; x [N,128], Wl/Wr [128,64] row-major
// block 256 = 8 rows x 32 col-groups(4 cols each, 0..15 -> Wl, 16..31 -> Wr)
__global__ void k_gemm1(const float* __restrict__ x, const float* __restrict__ Wl,
                        const float* __restrict__ Wr, float* __restrict__ xl,
                        float* __restrict__ xr, int N){
  __shared__ float xs[8][FIN];
  int tid = threadIdx.x;
  int cg = tid & 31, rloc = tid >> 5;
  for(int iter=0; iter<8; ++iter){
    int rowbase = blockIdx.x*64 + iter*8;
    __syncthreads();
    { int lrow = tid >> 5; int c4 = (tid & 31)*4;
      int row = rowbase + lrow;
      float4 v = make_float4(0.f,0.f,0.f,0.f);
      if(row < N) v = *(const float4*)(x + (size_t)row*FIN + c4);
      *(float4*)(&xs[lrow][c4]) = v; }
    __syncthreads();
    int row = rowbase + rloc;
    if(row < N){
      const float* Wb = (cg<16) ? (Wl + cg*4) : (Wr + (cg-16)*4);
      float a0=0.f,a1=0.f,a2=0.f,a3=0.f;
      #pragma unroll 4
      for(int k=0;k<FIN;k++){
        float xv = xs[rloc][k];
        float4 w = *(const float4*)(Wb + k*H);
        a0 += xv*w.x; a1 += xv*w.y; a2 += xv*w.z; a3 += xv*w.w;
      }
      float4 outv = make_float4(a0,a1,a2,a3);
      if(cg<16) *(float4*)(xl + (size_t)row*H + cg*4) = outv;
      else      *(float4*)(xr + (size_t)row*H + (cg-16)*4) = outv;
    }
  }
}

// K2: degree count (dst side, incl self-loops)
__global__ void k_degree(const int* __restrict__ ei, int E, int Etot, int* __restrict__ deg){
  int i = blockIdx.x*blockDim.x + threadIdx.x;
  int stride = gridDim.x*blockDim.x;
  for(; i<Etot; i+=stride){
    int dst = (i<E) ? ei[E+i] : (i-E);
    atomicAdd(&deg[dst], 1);
  }
}

// K3: exclusive scan over deg -> rowptr, single block of 1024
__global__ void k_scan(const int* __restrict__ deg, int* __restrict__ rowptr, int n){
  __shared__ int sums[1024];
  __shared__ int offs[1024];
  int tid = threadIdx.x;
  int chunk = (n + 1023)/1024;
  int start = tid*chunk; int end = min(start+chunk, n);
  int s=0;
  for(int i=start;i<end;i++) s += deg[i];
  sums[tid]=s;
  __syncthreads();
  if(tid==0){ int acc=0; for(int i=0;i<1024;i++){ offs[i]=acc; acc+=sums[i]; } rowptr[n]=acc; }
  __syncthreads();
  int acc = offs[tid];
  for(int i=start;i<end;i++){ rowptr[i]=acc; acc += deg[i]; }
}

// K4: CSR fill: csr_src[pos], pos_of_edge[orig_idx]
__global__ void k_fill(const int* __restrict__ ei, int E, int Etot,
                       const int* __restrict__ rowptr, int* __restrict__ cursor,
                       int* __restrict__ csr_src, int* __restrict__ pos_of_edge){
  int i = blockIdx.x*blockDim.x + threadIdx.x;
  int stride = gridDim.x*blockDim.x;
  for(; i<Etot; i+=stride){
    int src, dst;
    if(i<E){ src = ei[i]; dst = ei[E+i]; } else { src = i-E; dst = i-E; }
    int p = rowptr[dst] + atomicAdd(&cursor[dst],1);
    csr_src[p] = src;
    pos_of_edge[i] = p;
  }
}

// K5: layer-1 edge logits, one wave per edge, lane = feature
__global__ void k_edge1(const int* __restrict__ ei, int E, int Etot,
                        const float* __restrict__ xl, const float* __restrict__ xr,
                        const float* __restrict__ att,
                        const int* __restrict__ pos_of_edge,
                        float* __restrict__ e_csr){
  int widx = blockIdx.x*4 + (threadIdx.x>>6);
  int lane = threadIdx.x & 63;
  if(widx >= Etot) return;
  int src, dst;
  if(widx<E){ src = ei[widx]; dst = ei[E+widx]; } else { src = widx-E; dst = widx-E; }
  float v = xl[(size_t)src*H + lane] + xr[(size_t)dst*H + lane];
  v = (v>0.f)? v : NEG_SLOPE*v;
  float p = waveSum(v * att[lane]);
  if(lane==0) e_csr[pos_of_edge[widx]] = p;
}

// K6: layer-1 node softmax+aggregate, fused with layer-2 input GEMM (64->2 x2)
__global__ void k_node1(const int* __restrict__ rowptr, const int* __restrict__ csr_src,
                        const float* __restrict__ e_csr, const float* __restrict__ xl,
                        const float* __restrict__ b1,
                        const float* __restrict__ Wl2, const float* __restrict__ Wr2,
                        float* __restrict__ xl2, float* __restrict__ xr2, int N){
  int node = blockIdx.x*4 + (threadIdx.x>>6);
  int lane = threadIdx.x & 63;
  if(node >= N) return;
  int s = rowptr[node], t = rowptr[node+1];
  float m = -INFINITY;
  for(int k=s+lane; k<t; k+=64) m = fmaxf(m, e_csr[k]);
  m = waveMax(m);
  float acc = 0.f, denom = 0.f;
  for(int k=s; k<t; k++){
    float ex = expf(e_csr[k] - m);   // broadcast load, all lanes same value
    denom += ex;
    int src = csr_src[k];
    acc += ex * xl[(size_t)src*H + lane];
  }
  float h = acc/(denom + EPS) + b1[lane];
  float s0 = waveSum(h * Wl2[lane*FOUT+0]);
  float s1 = waveSum(h * Wl2[lane*FOUT+1]);
  float s2 = waveSum(h * Wr2[lane*FOUT+0]);
  float s3 = waveSum(h * Wr2[lane*FOUT+1]);
  if(lane==0){
    xl2[node*2+0]=s0; xl2[node*2+1]=s1;
    xr2[node*2+0]=s2; xr2[node*2+1]=s3;
  }
}

// K7: layer-2 full conv (logit recompute inline, F=2), wave per node, lanes over edges
__global__ void k_node2(const int* __restrict__ rowptr, const int* __restrict__ csr_src,
                        const float* __restrict__ xl2, const float* __restrict__ xr2,
                        const float* __restrict__ att2, const float* __restrict__ b2,
                        float* __restrict__ out, int N){
  int node = blockIdx.x*4 + (threadIdx.x>>6);
  int lane = threadIdx.x & 63;
  if(node >= N) return;
  int s = rowptr[node], t = rowptr[node+1];
  float xr0 = xr2[node*2+0], xr1v = xr2[node*2+1];
  float a0 = att2[0], a1 = att2[1];
  float m = -INFINITY;
  for(int k=s+lane; k<t; k+=64){
    int src = csr_src[k];
    float h0 = xl2[src*2+0] + xr0, h1 = xl2[src*2+1] + xr1v;
    h0 = (h0>0.f)? h0 : NEG_SLOPE*h0;
    h1 = (h1>0.f)? h1 : NEG_SLOPE*h1;
    m = fmaxf(m, h0*a0 + h1*a1);
  }
  m = waveMax(m);
  float den=0.f, n0=0.f, n1=0.f;
  for(int k=s+lane; k<t; k+=64){
    int src = csr_src[k];
    float xs0 = xl2[src*2+0], xs1 = xl2[src*2+1];
    float h0 = xs0 + xr0, h1 = xs1 + xr1v;
    float l0 = (h0>0.f)? h0 : NEG_SLOPE*h0;
    float l1 = (h1>0.f)? h1 : NEG_SLOPE*h1;
    float ex = expf(l0*a0 + l1*a1 - m);
    den += ex; n0 += ex*xs0; n1 += ex*xs1;
  }
  den = waveSum(den); n0 = waveSum(n0); n1 = waveSum(n1);
  if(lane==0){
    float inv = 1.f/(den + EPS);
    out[node*2+0] = n0*inv + b2[0];
    out[node*2+1] = n1*inv + b2[1];
  }
}

extern "C" void kernel_launch(void* const* d_in, const int* in_sizes, int n_in,
                              void* d_out, int out_size, void* d_ws, size_t ws_size,
                              hipStream_t stream){
  const float* x    = (const float*)d_in[0];
  const int*   ei   = (const int*)d_in[1];
  const float* Wl1  = (const float*)d_in[2];
  const float* Wr1  = (const float*)d_in[3];
  const float* att1 = (const float*)d_in[4];
  const float* b1   = (const float*)d_in[5];
  const float* Wl2  = (const float*)d_in[6];
  const float* Wr2  = (const float*)d_in[7];
  const float* att2 = (const float*)d_in[8];
  const float* b2   = (const float*)d_in[9];
  int N = in_sizes[0]/FIN;
  int E = in_sizes[1]/2;
  int Etot = E + N;

  char* w = (char*)d_ws;
  size_t off = 0;
  auto alloc = [&](size_t bytes)->void*{
    void* p = w + off;
    off = (off + bytes + 255) & ~(size_t)255;
    return p;
  };
  float* xl1    = (float*)alloc((size_t)N*H*4);
  float* xr1    = (float*)alloc((size_t)N*H*4);
  float* e_csr  = (float*)alloc((size_t)Etot*4);
  int*   csr_src= (int*)  alloc((size_t)Etot*4);
  int*   pos    = (int*)  alloc((size_t)Etot*4);
  int*   deg    = (int*)  alloc((size_t)N*4);
  int*   rowptr = (int*)  alloc((size_t)(N+1)*4);
  int*   cursor = (int*)  alloc((size_t)N*4);
  float* xl2    = (float*)alloc((size_t)N*2*4);
  float* xr2    = (float*)alloc((size_t)N*2*4);

  k_zero_int<<<256,256,0,stream>>>(deg, N);
  k_zero_int<<<256,256,0,stream>>>(cursor, N);
  k_gemm1<<<(N+63)/64, 256, 0, stream>>>(x, Wl1, Wr1, xl1, xr1, N);
  k_degree<<<1024,256,0,stream>>>(ei, E, Etot, deg);
  k_scan<<<1,1024,0,stream>>>(deg, rowptr, N);
  k_fill<<<1024,256,0,stream>>>(ei, E, Etot, rowptr, cursor, csr_src, pos);
  k_edge1<<<(Etot+3)/4, 256, 0, stream>>>(ei, E, Etot, xl1, xr1, att1, pos, e_csr);
  k_node1<<<(N+3)/4, 256, 0, stream>>>(rowptr, csr_src, e_csr, xl1, b1, Wl2, Wr2, xl2, xr2, N);
  k_node2<<<(N+3)/4, 256, 0, stream>>>(rowptr, csr_src, xl2, xr2, att2, b2, (float*)d_out, N);
}

// Round 2
// 353.894 us; speedup vs baseline: 1.6145x; 1.6145x over previous
//
#include <hip/hip_runtime.h>
#include <math.h>

#define FIN 128
#define H 64
#define FOUT 2
#define NEG_SLOPE 0.2f
#define EPS 1e-16f
#define MNEG -1e30f

__device__ __forceinline__ float waveSum(float v){
  #pragma unroll
  for(int o=1;o<64;o<<=1) v += __shfl_xor(v,o);
  return v;
}
__device__ __forceinline__ float waveMax(float v){
  #pragma unroll
  for(int o=1;o<64;o<<=1) v = fmaxf(v, __shfl_xor(v,o));
  return v;
}

// K0: zero int buffer
__global__ void k_zero_int(int* __restrict__ a, int n){
  int i = blockIdx.x*blockDim.x + threadIdx.x;
  int stride = gridDim.x*blockDim.x;
  for(; i<n; i+=stride) a[i]=0;
}

// K1: xl = x@Wl, xr = x@Wr ; x [N,128], Wl/Wr [128,64] row-major
__global__ void k_gemm1(const float* __restrict__ x, const float* __restrict__ Wl,
                        const float* __restrict__ Wr, float* __restrict__ xl,
                        float* __restrict__ xr, int N){
  __shared__ float xs[8][FIN];
  int tid = threadIdx.x;
  int cg = tid & 31, rloc = tid >> 5;
  for(int iter=0; iter<8; ++iter){
    int rowbase = blockIdx.x*64 + iter*8;
    __syncthreads();
    { int lrow = tid >> 5; int c4 = (tid & 31)*4;
      int row = rowbase + lrow;
      float4 v = make_float4(0.f,0.f,0.f,0.f);
      if(row < N) v = *(const float4*)(x + (size_t)row*FIN + c4);
      *(float4*)(&xs[lrow][c4]) = v; }
    __syncthreads();
    int row = rowbase + rloc;
    if(row < N){
      const float* Wb = (cg<16) ? (Wl + cg*4) : (Wr + (cg-16)*4);
      float a0=0.f,a1=0.f,a2=0.f,a3=0.f;
      #pragma unroll 4
      for(int k=0;k<FIN;k++){
        float xv = xs[rloc][k];
        float4 w = *(const float4*)(Wb + k*H);
        a0 += xv*w.x; a1 += xv*w.y; a2 += xv*w.z; a3 += xv*w.w;
      }
      float4 outv = make_float4(a0,a1,a2,a3);
      if(cg<16) *(float4*)(xl + (size_t)row*H + cg*4) = outv;
      else      *(float4*)(xr + (size_t)row*H + (cg-16)*4) = outv;
    }
  }
}

// K2: degree count (dst side, incl self-loops)
__global__ void k_degree(const int* __restrict__ ei, int E, int Etot, int* __restrict__ deg){
  int i = blockIdx.x*blockDim.x + threadIdx.x;
  int stride = gridDim.x*blockDim.x;
  for(; i<Etot; i+=stride){
    int dst = (i<E) ? ei[E+i] : (i-E);
    atomicAdd(&deg[dst], 1);
  }
}

// K3: exclusive scan over deg -> rowptr, single block of 1024, shuffle-based
__global__ void k_scan(const int* __restrict__ deg, int* __restrict__ rowptr, int n){
  __shared__ int warpsum[16];
  int tid = threadIdx.x;           // 1024
  int lane = tid & 63, wid = tid >> 6;
  int chunk = (n + 1023)/1024;
  int start = min(tid*chunk, n), end = min(start+chunk, n);
  int s=0;
  for(int i=start;i<end;i++) s += deg[i];
  // inclusive scan of per-thread sums within wave
  int v = s;
  #pragma unroll
  for(int o=1;o<64;o<<=1){ int u = __shfl_up(v,o); if(lane>=o) v += u; }
  if(lane==63) warpsum[wid]=v;
  __syncthreads();
  if(wid==0 && lane<16){
    int w = warpsum[lane];
    #pragma unroll
    for(int o=1;o<16;o<<=1){ int u=__shfl_up(w,o); if(lane>=o) w+=u; }
    warpsum[lane]=w;
  }
  __syncthreads();
  int base = (wid>0 ? warpsum[wid-1] : 0) + (v - s);  // exclusive offset
  int acc = base;
  for(int i=start;i<end;i++){ rowptr[i]=acc; acc+=deg[i]; }
  if(tid==1023) rowptr[n]=acc;
}

// K4: CSR fill
__global__ void k_fill(const int* __restrict__ ei, int E, int Etot,
                       const int* __restrict__ rowptr, int* __restrict__ cursor,
                       int* __restrict__ csr_src){
  int i = blockIdx.x*blockDim.x + threadIdx.x;
  int stride = gridDim.x*blockDim.x;
  for(; i<Etot; i+=stride){
    int src, dst;
    if(i<E){ src = ei[i]; dst = ei[E+i]; } else { src = i-E; dst = i-E; }
    int p = rowptr[dst] + atomicAdd(&cursor[dst],1);
    csr_src[p] = src;
  }
}

// K5: fused layer-1: edge logits + online softmax + aggregate + layer-2 projection.
// One wave per node; 4 groups of 16 lanes; each group processes one edge/iter;
// lane covers 4 features (float4), H=64 = 16 lanes * 4.
__global__ void k_node1f(const int* __restrict__ rowptr, const int* __restrict__ csr_src,
                         const float* __restrict__ xl, const float* __restrict__ xr,
                         const float* __restrict__ att, const float* __restrict__ b1,
                         const float* __restrict__ Wl2, const float* __restrict__ Wr2,
                         float* __restrict__ xl2, float* __restrict__ xr2, int N){
  int node = blockIdx.x*4 + (threadIdx.x>>6);
  int lane = threadIdx.x & 63;
  if(node >= N) return;
  int g  = lane >> 4;       // edge group 0..3
  int f4 = (lane & 15) * 4; // feature base
  float4 attv = *(const float4*)(att + f4);
  float4 xrv  = *(const float4*)(xr + (size_t)node*H + f4);
  int s = rowptr[node], t = rowptr[node+1];
  float m = MNEG, d = 0.f;
  float ax=0.f, ay=0.f, az=0.f, aw=0.f;
  for(int k = s + g; k < t; k += 4){
    int src = csr_src[k];
    float4 xv = *(const float4*)(xl + (size_t)src*H + f4);
    float h0 = xv.x + xrv.x, h1 = xv.y + xrv.y, h2 = xv.z + xrv.z, h3 = xv.w + xrv.w;
    float l0 = (h0>0.f)? h0 : NEG_SLOPE*h0;
    float l1 = (h1>0.f)? h1 : NEG_SLOPE*h1;
    float l2 = (h2>0.f)? h2 : NEG_SLOPE*h2;
    float l3 = (h3>0.f)? h3 : NEG_SLOPE*h3;
    float e = l0*attv.x + l1*attv.y + l2*attv.z + l3*attv.w;
    #pragma unroll
    for(int o=1;o<16;o<<=1) e += __shfl_xor(e,o);
    float M  = fmaxf(m, e);
    float sc = __expf(m - M);
    float w  = __expf(e - M);
    d  = d*sc + w;
    ax = ax*sc + w*xv.x; ay = ay*sc + w*xv.y;
    az = az*sc + w*xv.z; aw = aw*sc + w*xv.w;
    m = M;
  }
  // merge 4 group states across the wave (xor 16, 32)
  #pragma unroll
  for(int o=16;o<64;o<<=1){
    float m2 = __shfl_xor(m,o);
    float d2 = __shfl_xor(d,o);
    float bx = __shfl_xor(ax,o), by = __shfl_xor(ay,o);
    float bz = __shfl_xor(az,o), bw = __shfl_xor(aw,o);
    float M  = fmaxf(m, m2);
    float s1 = __expf(m - M), s2 = __expf(m2 - M);
    d  = d*s1 + d2*s2;
    ax = ax*s1 + bx*s2; ay = ay*s1 + by*s2;
    az = az*s1 + bz*s2; aw = aw*s1 + bw*s2;
    m = M;
  }
  float inv = 1.f/(d + EPS);
  float4 bv = *(const float4*)(b1 + f4);
  float h0 = ax*inv + bv.x, h1 = ay*inv + bv.y;
  float h2 = az*inv + bv.z, h3 = aw*inv + bv.w;
  // layer-2 input projections: group g computes one of {Wl2 c0, Wl2 c1, Wr2 c0, Wr2 c1}
  const float* Wp = (g<2) ? Wl2 : Wr2;
  int col = g & 1;
  float p = h0*Wp[(f4+0)*FOUT+col] + h1*Wp[(f4+1)*FOUT+col]
          + h2*Wp[(f4+2)*FOUT+col] + h3*Wp[(f4+3)*FOUT+col];
  #pragma unroll
  for(int o=1;o<16;o<<=1) p += __shfl_xor(p,o);
  if((lane&15)==0){
    if(g==0)      xl2[node*2+0]=p;
    else if(g==1) xl2[node*2+1]=p;
    else if(g==2) xr2[node*2+0]=p;
    else          xr2[node*2+1]=p;
  }
}

// K7: layer-2 full conv (logit recompute inline, F=2), wave per node, lanes over edges
__global__ void k_node2(const int* __restrict__ rowptr, const int* __restrict__ csr_src,
                        const float* __restrict__ xl2, const float* __restrict__ xr2,
                        const float* __restrict__ att2, const float* __restrict__ b2,
                        float* __restrict__ out, int N){
  int node = blockIdx.x*4 + (threadIdx.x>>6);
  int lane = threadIdx.x & 63;
  if(node >= N) return;
  int s = rowptr[node], t = rowptr[node+1];
  float xr0 = xr2[node*2+0], xr1v = xr2[node*2+1];
  float a0 = att2[0], a1 = att2[1];
  float m = MNEG;
  for(int k=s+lane; k<t; k+=64){
    int src = csr_src[k];
    float h0 = xl2[src*2+0] + xr0, h1 = xl2[src*2+1] + xr1v;
    h0 = (h0>0.f)? h0 : NEG_SLOPE*h0;
    h1 = (h1>0.f)? h1 : NEG_SLOPE*h1;
    m = fmaxf(m, h0*a0 + h1*a1);
  }
  m = waveMax(m);
  float den=0.f, n0=0.f, n1=0.f;
  for(int k=s+lane; k<t; k+=64){
    int src = csr_src[k];
    float xs0 = xl2[src*2+0], xs1 = xl2[src*2+1];
    float h0 = xs0 + xr0, h1 = xs1 + xr1v;
    float l0 = (h0>0.f)? h0 : NEG_SLOPE*h0;
    float l1 = (h1>0.f)? h1 : NEG_SLOPE*h1;
    float ex = __expf(l0*a0 + l1*a1 - m);
    den += ex; n0 += ex*xs0; n1 += ex*xs1;
  }
  den = waveSum(den); n0 = waveSum(n0); n1 = waveSum(n1);
  if(lane==0){
    float inv = 1.f/(den + EPS);
    out[node*2+0] = n0*inv + b2[0];
    out[node*2+1] = n1*inv + b2[1];
  }
}

extern "C" void kernel_launch(void* const* d_in, const int* in_sizes, int n_in,
                              void* d_out, int out_size, void* d_ws, size_t ws_size,
                              hipStream_t stream){
  const float* x    = (const float*)d_in[0];
  const int*   ei   = (const int*)d_in[1];
  const float* Wl1  = (const float*)d_in[2];
  const float* Wr1  = (const float*)d_in[3];
  const float* att1 = (const float*)d_in[4];
  const float* b1   = (const float*)d_in[5];
  const float* Wl2  = (const float*)d_in[6];
  const float* Wr2  = (const float*)d_in[7];
  const float* att2 = (const float*)d_in[8];
  const float* b2   = (const float*)d_in[9];
  int N = in_sizes[0]/FIN;
  int E = in_sizes[1]/2;
  int Etot = E + N;

  char* w = (char*)d_ws;
  size_t off = 0;
  auto alloc = [&](size_t bytes)->void*{
    void* p = w + off;
    off = (off + bytes + 255) & ~(size_t)255;
    return p;
  };
  float* xl1    = (float*)alloc((size_t)N*H*4);
  float* xr1    = (float*)alloc((size_t)N*H*4);
  int*   csr_src= (int*)  alloc((size_t)Etot*4);
  int*   deg    = (int*)  alloc((size_t)N*4);      // deg+cursor adjacent: one zero pass
  int*   cursor = (int*)  alloc((size_t)N*4);
  int*   rowptr = (int*)  alloc((size_t)(N+1)*4);
  float* xl2    = (float*)alloc((size_t)N*2*4);
  float* xr2    = (float*)alloc((size_t)N*2*4);

  k_zero_int<<<256,256,0,stream>>>(deg, 2*N + 64);   // zeros deg and cursor (adjacent, 256B-pad safe)
  k_gemm1<<<(N+63)/64, 256, 0, stream>>>(x, Wl1, Wr1, xl1, xr1, N);
  k_degree<<<1024,256,0,stream>>>(ei, E, Etot, deg);
  k_scan<<<1,1024,0,stream>>>(deg, rowptr, N);
  k_fill<<<1024,256,0,stream>>>(ei, E, Etot, rowptr, cursor, csr_src);
  k_node1f<<<(N+3)/4, 256, 0, stream>>>(rowptr, csr_src, xl1, xr1, att1, b1, Wl2, Wr2, xl2, xr2, N);
  k_node2<<<(N+3)/4, 256, 0, stream>>>(rowptr, csr_src, xl2, xr2, att2, b2, (float*)d_out, N);
}

// Round 3
// 276.871 us; speedup vs baseline: 2.0637x; 1.2782x over previous
//
#include <hip/hip_runtime.h>
#include <math.h>

#define FIN 128
#define H 64
#define FOUT 2
#define NEG_SLOPE 0.2f
#define EPS 1e-16f
#define MNEG -1e30f

#define BM 128
#define BK 32

__device__ __forceinline__ float waveSum(float v){
  #pragma unroll
  for(int o=1;o<64;o<<=1) v += __shfl_xor(v,o);
  return v;
}
__device__ __forceinline__ float waveMax(float v){
  #pragma unroll
  for(int o=1;o<64;o<<=1) v = fmaxf(v, __shfl_xor(v,o));
  return v;
}

// K0: zero int buffer
__global__ void k_zero_int(int* __restrict__ a, int n){
  int i = blockIdx.x*blockDim.x + threadIdx.x;
  int stride = gridDim.x*blockDim.x;
  for(; i<n; i+=stride) a[i]=0;
}

// K1: [N,128] @ [128, 64|64] -> xl, xr.  LDS-tiled, 8x8 register micro-tile.
// Thread (tc,tr): rows r0=tr*8..+7, cols Wl[c0..c0+3] and Wr[c0..c0+3], c0=tc*4.
__global__ __launch_bounds__(256) void k_gemm1(
    const float* __restrict__ x, const float* __restrict__ Wl,
    const float* __restrict__ Wr, float* __restrict__ xl,
    float* __restrict__ xr, int N){
  __shared__ float xsT[BK][BM+4];   // [kk][row] transposed, pad 4
  __shared__ float ws[BK][128];     // [kk][col], col<64 Wl else Wr
  int tid = threadIdx.x;
  int rowbase = blockIdx.x*BM;
  int tc = tid & 15, tr = tid >> 4;        // tr in [0,16)
  int r0 = tr*8, c0 = tc*4;
  float acc[8][8];
  #pragma unroll
  for(int i=0;i<8;i++)
    #pragma unroll
    for(int j=0;j<8;j++) acc[i][j]=0.f;

  int lrow = tid >> 1;            // 0..127 (x stage row)
  int lk16 = (tid & 1) * 16;      // k-offset 0 or 16
  int wkk  = tid >> 3;            // 0..31 (W stage row)
  int wfq  = tid & 7;             // 0..7

  for(int k0=0; k0<FIN; k0+=BK){
    __syncthreads();
    // stage x tile (transposed)
    {
      int grow = rowbase + lrow;
      #pragma unroll
      for(int q=0;q<2;q++){
        int kc = lk16 + q*8;
        float4 v0 = make_float4(0,0,0,0), v1 = make_float4(0,0,0,0);
        if(grow < N){
          v0 = *(const float4*)(x + (size_t)grow*FIN + k0 + kc);
          v1 = *(const float4*)(x + (size_t)grow*FIN + k0 + kc + 4);
        }
        xsT[kc+0][lrow]=v0.x; xsT[kc+1][lrow]=v0.y; xsT[kc+2][lrow]=v0.z; xsT[kc+3][lrow]=v0.w;
        xsT[kc+4][lrow]=v1.x; xsT[kc+5][lrow]=v1.y; xsT[kc+6][lrow]=v1.z; xsT[kc+7][lrow]=v1.w;
      }
    }
    // stage W tile: ws[wkk][c4], c4 = (wfq+i*8)*4
    #pragma unroll
    for(int i=0;i<4;i++){
      int c4 = (wfq + i*8)*4;
      const float* srcp = (c4 < 64) ? (Wl + (size_t)(k0+wkk)*H + c4)
                                    : (Wr + (size_t)(k0+wkk)*H + (c4-64));
      *(float4*)(&ws[wkk][c4]) = *(const float4*)srcp;
    }
    __syncthreads();
    #pragma unroll
    for(int kk=0; kk<BK; kk++){
      float4 a0 = *(float4*)(&xsT[kk][r0]);
      float4 a1 = *(float4*)(&xsT[kk][r0+4]);
      float4 b0 = *(float4*)(&ws[kk][c0]);        // Wl cols
      float4 b1 = *(float4*)(&ws[kk][64+c0]);     // Wr cols
      float a[8] = {a0.x,a0.y,a0.z,a0.w,a1.x,a1.y,a1.z,a1.w};
      float b[8] = {b0.x,b0.y,b0.z,b0.w,b1.x,b1.y,b1.z,b1.w};
      #pragma unroll
      for(int i=0;i<8;i++)
        #pragma unroll
        for(int j=0;j<8;j++)
          acc[i][j] += a[i]*b[j];
    }
  }
  #pragma unroll
  for(int i=0;i<8;i++){
    int row = rowbase + r0 + i;
    if(row < N){
      *(float4*)(xl + (size_t)row*H + c0) = make_float4(acc[i][0],acc[i][1],acc[i][2],acc[i][3]);
      *(float4*)(xr + (size_t)row*H + c0) = make_float4(acc[i][4],acc[i][5],acc[i][6],acc[i][7]);
    }
  }
}

// K2: degree count (dst side, incl self-loops)
__global__ void k_degree(const int* __restrict__ ei, int E, int Etot, int* __restrict__ deg){
  int i = blockIdx.x*blockDim.x + threadIdx.x;
  int stride = gridDim.x*blockDim.x;
  for(; i<Etot; i+=stride){
    int dst = (i<E) ? ei[E+i] : (i-E);
    atomicAdd(&deg[dst], 1);
  }
}

// K3: exclusive scan over deg -> rowptr, single block of 1024, shuffle-based
__global__ void k_scan(const int* __restrict__ deg, int* __restrict__ rowptr, int n){
  __shared__ int warpsum[16];
  int tid = threadIdx.x;           // 1024
  int lane = tid & 63, wid = tid >> 6;
  int chunk = (n + 1023)/1024;
  int start = min(tid*chunk, n), end = min(start+chunk, n);
  int s=0;
  for(int i=start;i<end;i++) s += deg[i];
  int v = s;
  #pragma unroll
  for(int o=1;o<64;o<<=1){ int u = __shfl_up(v,o); if(lane>=o) v += u; }
  if(lane==63) warpsum[wid]=v;
  __syncthreads();
  if(wid==0 && lane<16){
    int w = warpsum[lane];
    #pragma unroll
    for(int o=1;o<16;o<<=1){ int u=__shfl_up(w,o); if(lane>=o) w+=u; }
    warpsum[lane]=w;
  }
  __syncthreads();
  int base = (wid>0 ? warpsum[wid-1] : 0) + (v - s);
  int acc = base;
  for(int i=start;i<end;i++){ rowptr[i]=acc; acc+=deg[i]; }
  if(tid==1023) rowptr[n]=acc;
}

// K4: CSR fill
__global__ void k_fill(const int* __restrict__ ei, int E, int Etot,
                       const int* __restrict__ rowptr, int* __restrict__ cursor,
                       int* __restrict__ csr_src){
  int i = blockIdx.x*blockDim.x + threadIdx.x;
  int stride = gridDim.x*blockDim.x;
  for(; i<Etot; i+=stride){
    int src, dst;
    if(i<E){ src = ei[i]; dst = ei[E+i]; } else { src = i-E; dst = i-E; }
    int p = rowptr[dst] + atomicAdd(&cursor[dst],1);
    csr_src[p] = src;
  }
}

// K5: fused layer-1: edge logits + online softmax + aggregate + layer-2 projection.
__global__ void k_node1f(const int* __restrict__ rowptr, const int* __restrict__ csr_src,
                         const float* __restrict__ xl, const float* __restrict__ xr,
                         const float* __restrict__ att, const float* __restrict__ b1,
                         const float* __restrict__ Wl2, const float* __restrict__ Wr2,
                         float* __restrict__ xl2, float* __restrict__ xr2, int N){
  int node = blockIdx.x*4 + (threadIdx.x>>6);
  int lane = threadIdx.x & 63;
  if(node >= N) return;
  int g  = lane >> 4;       // edge group 0..3
  int f4 = (lane & 15) * 4; // feature base
  float4 attv = *(const float4*)(att + f4);
  float4 xrv  = *(const float4*)(xr + (size_t)node*H + f4);
  int s = rowptr[node], t = rowptr[node+1];
  float m = MNEG, d = 0.f;
  float ax=0.f, ay=0.f, az=0.f, aw=0.f;
  for(int k = s + g; k < t; k += 4){
    int src = csr_src[k];
    float4 xv = *(const float4*)(xl + (size_t)src*H + f4);
    float h0 = xv.x + xrv.x, h1 = xv.y + xrv.y, h2 = xv.z + xrv.z, h3 = xv.w + xrv.w;
    float l0 = (h0>0.f)? h0 : NEG_SLOPE*h0;
    float l1 = (h1>0.f)? h1 : NEG_SLOPE*h1;
    float l2 = (h2>0.f)? h2 : NEG_SLOPE*h2;
    float l3 = (h3>0.f)? h3 : NEG_SLOPE*h3;
    float e = l0*attv.x + l1*attv.y + l2*attv.z + l3*attv.w;
    #pragma unroll
    for(int o=1;o<16;o<<=1) e += __shfl_xor(e,o);
    float M  = fmaxf(m, e);
    float sc = __expf(m - M);
    float w  = __expf(e - M);
    d  = d*sc + w;
    ax = ax*sc + w*xv.x; ay = ay*sc + w*xv.y;
    az = az*sc + w*xv.z; aw = aw*sc + w*xv.w;
    m = M;
  }
  #pragma unroll
  for(int o=16;o<64;o<<=1){
    float m2 = __shfl_xor(m,o);
    float d2 = __shfl_xor(d,o);
    float bx = __shfl_xor(ax,o), by = __shfl_xor(ay,o);
    float bz = __shfl_xor(az,o), bw = __shfl_xor(aw,o);
    float M  = fmaxf(m, m2);
    float s1 = __expf(m - M), s2 = __expf(m2 - M);
    d  = d*s1 + d2*s2;
    ax = ax*s1 + bx*s2; ay = ay*s1 + by*s2;
    az = az*s1 + bz*s2; aw = aw*s1 + bw*s2;
    m = M;
  }
  float inv = 1.f/(d + EPS);
  float4 bv = *(const float4*)(b1 + f4);
  float h0 = ax*inv + bv.x, h1 = ay*inv + bv.y;
  float h2 = az*inv + bv.z, h3 = aw*inv + bv.w;
  const float* Wp = (g<2) ? Wl2 : Wr2;
  int col = g & 1;
  float p = h0*Wp[(f4+0)*FOUT+col] + h1*Wp[(f4+1)*FOUT+col]
          + h2*Wp[(f4+2)*FOUT+col] + h3*Wp[(f4+3)*FOUT+col];
  #pragma unroll
  for(int o=1;o<16;o<<=1) p += __shfl_xor(p,o);
  if((lane&15)==0){
    if(g==0)      xl2[node*2+0]=p;
    else if(g==1) xl2[node*2+1]=p;
    else if(g==2) xr2[node*2+0]=p;
    else          xr2[node*2+1]=p;
  }
}

// K7: layer-2 full conv (logit recompute inline, F=2)
__global__ void k_node2(const int* __restrict__ rowptr, const int* __restrict__ csr_src,
                        const float* __restrict__ xl2, const float* __restrict__ xr2,
                        const float* __restrict__ att2, const float* __restrict__ b2,
                        float* __restrict__ out, int N){
  int node = blockIdx.x*4 + (threadIdx.x>>6);
  int lane = threadIdx.x & 63;
  if(node >= N) return;
  int s = rowptr[node], t = rowptr[node+1];
  float xr0 = xr2[node*2+0], xr1v = xr2[node*2+1];
  float a0 = att2[0], a1 = att2[1];
  float m = MNEG;
  for(int k=s+lane; k<t; k+=64){
    int src = csr_src[k];
    float h0 = xl2[src*2+0] + xr0, h1 = xl2[src*2+1] + xr1v;
    h0 = (h0>0.f)? h0 : NEG_SLOPE*h0;
    h1 = (h1>0.f)? h1 : NEG_SLOPE*h1;
    m = fmaxf(m, h0*a0 + h1*a1);
  }
  m = waveMax(m);
  float den=0.f, n0=0.f, n1=0.f;
  for(int k=s+lane; k<t; k+=64){
    int src = csr_src[k];
    float xs0 = xl2[src*2+0], xs1 = xl2[src*2+1];
    float h0 = xs0 + xr0, h1 = xs1 + xr1v;
    float l0 = (h0>0.f)? h0 : NEG_SLOPE*h0;
    float l1 = (h1>0.f)? h1 : NEG_SLOPE*h1;
    float ex = __expf(l0*a0 + l1*a1 - m);
    den += ex; n0 += ex*xs0; n1 += ex*xs1;
  }
  den = waveSum(den); n0 = waveSum(n0); n1 = waveSum(n1);
  if(lane==0){
    float inv = 1.f/(den + EPS);
    out[node*2+0] = n0*inv + b2[0];
    out[node*2+1] = n1*inv + b2[1];
  }
}

extern "C" void kernel_launch(void* const* d_in, const int* in_sizes, int n_in,
                              void* d_out, int out_size, void* d_ws, size_t ws_size,
                              hipStream_t stream){
  const float* x    = (const float*)d_in[0];
  const int*   ei   = (const int*)d_in[1];
  const float* Wl1  = (const float*)d_in[2];
  const float* Wr1  = (const float*)d_in[3];
  const float* att1 = (const float*)d_in[4];
  const float* b1   = (const float*)d_in[5];
  const float* Wl2  = (const float*)d_in[6];
  const float* Wr2  = (const float*)d_in[7];
  const float* att2 = (const float*)d_in[8];
  const float* b2   = (const float*)d_in[9];
  int N = in_sizes[0]/FIN;
  int E = in_sizes[1]/2;
  int Etot = E + N;

  char* w = (char*)d_ws;
  size_t off = 0;
  auto alloc = [&](size_t bytes)->void*{
    void* p = w + off;
    off = (off + bytes + 255) & ~(size_t)255;
    return p;
  };
  float* xl1    = (float*)alloc((size_t)N*H*4);
  float* xr1    = (float*)alloc((size_t)N*H*4);
  int*   csr_src= (int*)  alloc((size_t)Etot*4);
  int*   deg    = (int*)  alloc((size_t)N*4);
  int*   cursor = (int*)  alloc((size_t)N*4);
  int*   rowptr = (int*)  alloc((size_t)(N+1)*4);
  float* xl2    = (float*)alloc((size_t)N*2*4);
  float* xr2    = (float*)alloc((size_t)N*2*4);

  k_zero_int<<<256,256,0,stream>>>(deg, 2*N + 64);   // zeros deg + cursor (adjacent)
  k_gemm1<<<(N+BM-1)/BM, 256, 0, stream>>>(x, Wl1, Wr1, xl1, xr1, N);
  k_degree<<<1024,256,0,stream>>>(ei, E, Etot, deg);
  k_scan<<<1,1024,0,stream>>>(deg, rowptr, N);
  k_fill<<<1024,256,0,stream>>>(ei, E, Etot, rowptr, cursor, csr_src);
  k_node1f<<<(N+3)/4, 256, 0, stream>>>(rowptr, csr_src, xl1, xr1, att1, b1, Wl2, Wr2, xl2, xr2, N);
  k_node2<<<(N+3)/4, 256, 0, stream>>>(rowptr, csr_src, xl2, xr2, att2, b2, (float*)d_out, N);
}

// Round 4
// 209.904 us; speedup vs baseline: 2.7221x; 1.3190x over previous
//
#include <hip/hip_runtime.h>
#include <math.h>

#define FIN 128
#define H 64
#define FOUT 2
#define NEG_SLOPE 0.2f
#define EPS 1e-16f
#define MNEG -1e30f

#define BM 128
#define BK 32
#define SCAN_CHUNK 2048   // elements per scan_a block (256 thr * 8)

__device__ __forceinline__ float waveSum(float v){
  #pragma unroll
  for(int o=1;o<64;o<<=1) v += __shfl_xor(v,o);
  return v;
}
__device__ __forceinline__ float waveMax(float v){
  #pragma unroll
  for(int o=1;o<64;o<<=1) v = fmaxf(v, __shfl_xor(v,o));
  return v;
}

// K0: zero int buffer
__global__ void k_zero_int(int* __restrict__ a, int n){
  int i = blockIdx.x*blockDim.x + threadIdx.x;
  int stride = gridDim.x*blockDim.x;
  for(; i<n; i+=stride) a[i]=0;
}

// K1: [N,128] @ [128, 64|64] -> xl, xr.  LDS-tiled, 8x8 register micro-tile.
__global__ __launch_bounds__(256) void k_gemm1(
    const float* __restrict__ x, const float* __restrict__ Wl,
    const float* __restrict__ Wr, float* __restrict__ xl,
    float* __restrict__ xr, int N){
  __shared__ float xsT[BK][BM+4];
  __shared__ float ws[BK][128];
  int tid = threadIdx.x;
  int rowbase = blockIdx.x*BM;
  int tc = tid & 15, tr = tid >> 4;
  int r0 = tr*8, c0 = tc*4;
  float acc[8][8];
  #pragma unroll
  for(int i=0;i<8;i++)
    #pragma unroll
    for(int j=0;j<8;j++) acc[i][j]=0.f;

  int lrow = tid >> 1;
  int lk16 = (tid & 1) * 16;
  int wkk  = tid >> 3;
  int wfq  = tid & 7;

  for(int k0=0; k0<FIN; k0+=BK){
    __syncthreads();
    {
      int grow = rowbase + lrow;
      #pragma unroll
      for(int q=0;q<2;q++){
        int kc = lk16 + q*8;
        float4 v0 = make_float4(0,0,0,0), v1 = make_float4(0,0,0,0);
        if(grow < N){
          v0 = *(const float4*)(x + (size_t)grow*FIN + k0 + kc);
          v1 = *(const float4*)(x + (size_t)grow*FIN + k0 + kc + 4);
        }
        xsT[kc+0][lrow]=v0.x; xsT[kc+1][lrow]=v0.y; xsT[kc+2][lrow]=v0.z; xsT[kc+3][lrow]=v0.w;
        xsT[kc+4][lrow]=v1.x; xsT[kc+5][lrow]=v1.y; xsT[kc+6][lrow]=v1.z; xsT[kc+7][lrow]=v1.w;
      }
    }
    #pragma unroll
    for(int i=0;i<4;i++){
      int c4 = (wfq + i*8)*4;
      const float* srcp = (c4 < 64) ? (Wl + (size_t)(k0+wkk)*H + c4)
                                    : (Wr + (size_t)(k0+wkk)*H + (c4-64));
      *(float4*)(&ws[wkk][c4]) = *(const float4*)srcp;
    }
    __syncthreads();
    #pragma unroll
    for(int kk=0; kk<BK; kk++){
      float4 a0 = *(float4*)(&xsT[kk][r0]);
      float4 a1 = *(float4*)(&xsT[kk][r0+4]);
      float4 b0 = *(float4*)(&ws[kk][c0]);
      float4 b1 = *(float4*)(&ws[kk][64+c0]);
      float a[8] = {a0.x,a0.y,a0.z,a0.w,a1.x,a1.y,a1.z,a1.w};
      float b[8] = {b0.x,b0.y,b0.z,b0.w,b1.x,b1.y,b1.z,b1.w};
      #pragma unroll
      for(int i=0;i<8;i++)
        #pragma unroll
        for(int j=0;j<8;j++)
          acc[i][j] += a[i]*b[j];
    }
  }
  #pragma unroll
  for(int i=0;i<8;i++){
    int row = rowbase + r0 + i;
    if(row < N){
      *(float4*)(xl + (size_t)row*H + c0) = make_float4(acc[i][0],acc[i][1],acc[i][2],acc[i][3]);
      *(float4*)(xr + (size_t)row*H + c0) = make_float4(acc[i][4],acc[i][5],acc[i][6],acc[i][7]);
    }
  }
}

// K2: degree count (dst side, incl self-loops)
__global__ void k_degree(const int* __restrict__ ei, int E, int Etot, int* __restrict__ deg){
  int i = blockIdx.x*blockDim.x + threadIdx.x;
  int stride = gridDim.x*blockDim.x;
  for(; i<Etot; i+=stride){
    int dst = (i<E) ? ei[E+i] : (i-E);
    atomicAdd(&deg[dst], 1);
  }
}

// K3a: per-block scan of deg (2048 elems/block), local-exclusive into rowptr, block totals
__global__ __launch_bounds__(256) void k_scan_a(const int* __restrict__ deg, int n,
                                                int* __restrict__ rowptr,
                                                int* __restrict__ blocksum){
  __shared__ int wsum[4];
  int tid = threadIdx.x, lane = tid & 63, wid = tid >> 6;
  int idx = blockIdx.x*SCAN_CHUNK + tid*8;
  int v[8];
  if(idx + 8 <= n){
    int4 a = *(const int4*)(deg + idx);
    int4 b = *(const int4*)(deg + idx + 4);
    v[0]=a.x;v[1]=a.y;v[2]=a.z;v[3]=a.w;v[4]=b.x;v[5]=b.y;v[6]=b.z;v[7]=b.w;
  } else {
    #pragma unroll
    for(int i=0;i<8;i++) v[i] = (idx+i<n)? deg[idx+i] : 0;
  }
  int pre[8]; int st=0;
  #pragma unroll
  for(int i=0;i<8;i++){ pre[i]=st; st+=v[i]; }
  int incl = st;
  #pragma unroll
  for(int o=1;o<64;o<<=1){ int u=__shfl_up(incl,o); if(lane>=o) incl+=u; }
  if(lane==63) wsum[wid]=incl;
  __syncthreads();
  if(tid==0){ int accu=0; for(int i=0;i<4;i++){ int t=wsum[i]; wsum[i]=accu; accu+=t; } }
  __syncthreads();
  int toff = wsum[wid] + incl - st;   // exclusive offset of this thread in block
  if(idx + 8 <= n){
    int4 o0 = make_int4(toff+pre[0],toff+pre[1],toff+pre[2],toff+pre[3]);
    int4 o1 = make_int4(toff+pre[4],toff+pre[5],toff+pre[6],toff+pre[7]);
    *(int4*)(rowptr+idx)=o0; *(int4*)(rowptr+idx+4)=o1;
  } else {
    #pragma unroll
    for(int i=0;i<8;i++) if(idx+i<n) rowptr[idx+i]=toff+pre[i];
  }
  if(tid==255) blocksum[blockIdx.x] = toff + st;
}

// K3b: exclusive scan of block sums (nb <= 64), total -> rowptr[n]
__global__ void k_scan_b(int* __restrict__ blocksum, int nb, int* __restrict__ rowptr, int n){
  int lane = threadIdx.x & 63;
  int v = (lane<nb)? blocksum[lane] : 0;
  int incl = v;
  #pragma unroll
  for(int o=1;o<64;o<<=1){ int u=__shfl_up(incl,o); if(lane>=o) incl+=u; }
  if(lane<nb) blocksum[lane] = incl - v;   // exclusive
  if(lane==63) rowptr[n] = incl;           // grand total
}

// K3c: add block offsets
__global__ void k_scan_c(int* __restrict__ rowptr, const int* __restrict__ blocksum, int n){
  int i = blockIdx.x*blockDim.x + threadIdx.x;
  if(i<n) rowptr[i] += blocksum[i >> 11];  // SCAN_CHUNK = 2048
}

// K4: CSR fill
__global__ void k_fill(const int* __restrict__ ei, int E, int Etot,
                       const int* __restrict__ rowptr, int* __restrict__ cursor,
                       int* __restrict__ csr_src){
  int i = blockIdx.x*blockDim.x + threadIdx.x;
  int stride = gridDim.x*blockDim.x;
  for(; i<Etot; i+=stride){
    int src, dst;
    if(i<E){ src = ei[i]; dst = ei[E+i]; } else { src = i-E; dst = i-E; }
    int p = rowptr[dst] + atomicAdd(&cursor[dst],1);
    csr_src[p] = src;
  }
}

// K5: fused layer-1: edge logits + online softmax + aggregate + layer-2 projection.
__global__ void k_node1f(const int* __restrict__ rowptr, const int* __restrict__ csr_src,
                         const float* __restrict__ xl, const float* __restrict__ xr,
                         const float* __restrict__ att, const float* __restrict__ b1,
                         const float* __restrict__ Wl2, const float* __restrict__ Wr2,
                         float* __restrict__ xl2, float* __restrict__ xr2, int N){
  int node = blockIdx.x*4 + (threadIdx.x>>6);
  int lane = threadIdx.x & 63;
  if(node >= N) return;
  int g  = lane >> 4;
  int f4 = (lane & 15) * 4;
  float4 attv = *(const float4*)(att + f4);
  float4 xrv  = *(const float4*)(xr + (size_t)node*H + f4);
  int s = rowptr[node], t = rowptr[node+1];
  float m = MNEG, d = 0.f;
  float ax=0.f, ay=0.f, az=0.f, aw=0.f;
  for(int k = s + g; k < t; k += 4){
    int src = csr_src[k];
    float4 xv = *(const float4*)(xl + (size_t)src*H + f4);
    float h0 = xv.x + xrv.x, h1 = xv.y + xrv.y, h2 = xv.z + xrv.z, h3 = xv.w + xrv.w;
    float l0 = (h0>0.f)? h0 : NEG_SLOPE*h0;
    float l1 = (h1>0.f)? h1 : NEG_SLOPE*h1;
    float l2 = (h2>0.f)? h2 : NEG_SLOPE*h2;
    float l3 = (h3>0.f)? h3 : NEG_SLOPE*h3;
    float e = l0*attv.x + l1*attv.y + l2*attv.z + l3*attv.w;
    #pragma unroll
    for(int o=1;o<16;o<<=1) e += __shfl_xor(e,o);
    float M  = fmaxf(m, e);
    float sc = __expf(m - M);
    float w  = __expf(e - M);
    d  = d*sc + w;
    ax = ax*sc + w*xv.x; ay = ay*sc + w*xv.y;
    az = az*sc + w*xv.z; aw = aw*sc + w*xv.w;
    m = M;
  }
  #pragma unroll
  for(int o=16;o<64;o<<=1){
    float m2 = __shfl_xor(m,o);
    float d2 = __shfl_xor(d,o);
    float bx = __shfl_xor(ax,o), by = __shfl_xor(ay,o);
    float bz = __shfl_xor(az,o), bw = __shfl_xor(aw,o);
    float M  = fmaxf(m, m2);
    float s1 = __expf(m - M), s2 = __expf(m2 - M);
    d  = d*s1 + d2*s2;
    ax = ax*s1 + bx*s2; ay = ay*s1 + by*s2;
    az = az*s1 + bz*s2; aw = aw*s1 + bw*s2;
    m = M;
  }
  float inv = 1.f/(d + EPS);
  float4 bv = *(const float4*)(b1 + f4);
  float h0 = ax*inv + bv.x, h1 = ay*inv + bv.y;
  float h2 = az*inv + bv.z, h3 = aw*inv + bv.w;
  const float* Wp = (g<2) ? Wl2 : Wr2;
  int col = g & 1;
  float p = h0*Wp[(f4+0)*FOUT+col] + h1*Wp[(f4+1)*FOUT+col]
          + h2*Wp[(f4+2)*FOUT+col] + h3*Wp[(f4+3)*FOUT+col];
  #pragma unroll
  for(int o=1;o<16;o<<=1) p += __shfl_xor(p,o);
  if((lane&15)==0){
    if(g==0)      xl2[node*2+0]=p;
    else if(g==1) xl2[node*2+1]=p;
    else if(g==2) xr2[node*2+0]=p;
    else          xr2[node*2+1]=p;
  }
}

// K7: layer-2 full conv (logit recompute inline, F=2)
__global__ void k_node2(const int* __restrict__ rowptr, const int* __restrict__ csr_src,
                        const float* __restrict__ xl2, const float* __restrict__ xr2,
                        const float* __restrict__ att2, const float* __restrict__ b2,
                        float* __restrict__ out, int N){
  int node = blockIdx.x*4 + (threadIdx.x>>6);
  int lane = threadIdx.x & 63;
  if(node >= N) return;
  int s = rowptr[node], t = rowptr[node+1];
  float xr0 = xr2[node*2+0], xr1v = xr2[node*2+1];
  float a0 = att2[0], a1 = att2[1];
  float m = MNEG;
  for(int k=s+lane; k<t; k+=64){
    int src = csr_src[k];
    float h0 = xl2[src*2+0] + xr0, h1 = xl2[src*2+1] + xr1v;
    h0 = (h0>0.f)? h0 : NEG_SLOPE*h0;
    h1 = (h1>0.f)? h1 : NEG_SLOPE*h1;
    m = fmaxf(m, h0*a0 + h1*a1);
  }
  m = waveMax(m);
  float den=0.f, n0=0.f, n1=0.f;
  for(int k=s+lane; k<t; k+=64){
    int src = csr_src[k];
    float xs0 = xl2[src*2+0], xs1 = xl2[src*2+1];
    float h0 = xs0 + xr0, h1 = xs1 + xr1v;
    float l0 = (h0>0.f)? h0 : NEG_SLOPE*h0;
    float l1 = (h1>0.f)? h1 : NEG_SLOPE*h1;
    float ex = __expf(l0*a0 + l1*a1 - m);
    den += ex; n0 += ex*xs0; n1 += ex*xs1;
  }
  den = waveSum(den); n0 = waveSum(n0); n1 = waveSum(n1);
  if(lane==0){
    float inv = 1.f/(den + EPS);
    out[node*2+0] = n0*inv + b2[0];
    out[node*2+1] = n1*inv + b2[1];
  }
}

extern "C" void kernel_launch(void* const* d_in, const int* in_sizes, int n_in,
                              void* d_out, int out_size, void* d_ws, size_t ws_size,
                              hipStream_t stream){
  const float* x    = (const float*)d_in[0];
  const int*   ei   = (const int*)d_in[1];
  const float* Wl1  = (const float*)d_in[2];
  const float* Wr1  = (const float*)d_in[3];
  const float* att1 = (const float*)d_in[4];
  const float* b1   = (const float*)d_in[5];
  const float* Wl2  = (const float*)d_in[6];
  const float* Wr2  = (const float*)d_in[7];
  const float* att2 = (const float*)d_in[8];
  const float* b2   = (const float*)d_in[9];
  int N = in_sizes[0]/FIN;
  int E = in_sizes[1]/2;
  int Etot = E + N;
  int nscan = (N + SCAN_CHUNK - 1) / SCAN_CHUNK;   // 25 for N=50000 (<=64 supported)

  char* w = (char*)d_ws;
  size_t off = 0;
  auto alloc = [&](size_t bytes)->void*{
    void* p = w + off;
    off = (off + bytes + 255) & ~(size_t)255;
    return p;
  };
  float* xl1     = (float*)alloc((size_t)N*H*4);
  float* xr1     = (float*)alloc((size_t)N*H*4);
  int*   csr_src = (int*)  alloc((size_t)Etot*4);
  int*   deg     = (int*)  alloc((size_t)N*4);
  int*   cursor  = (int*)  alloc((size_t)N*4);
  int*   rowptr  = (int*)  alloc((size_t)(N+1)*4);
  int*   blocksum= (int*)  alloc((size_t)64*4);
  float* xl2     = (float*)alloc((size_t)N*2*4);
  float* xr2     = (float*)alloc((size_t)N*2*4);

  k_zero_int<<<256,256,0,stream>>>(deg, 2*N + 64);   // zeros deg + cursor (adjacent)
  k_gemm1<<<(N+BM-1)/BM, 256, 0, stream>>>(x, Wl1, Wr1, xl1, xr1, N);
  k_degree<<<1024,256,0,stream>>>(ei, E, Etot, deg);
  k_scan_a<<<nscan,256,0,stream>>>(deg, N, rowptr, blocksum);
  k_scan_b<<<1,64,0,stream>>>(blocksum, nscan, rowptr, N);
  k_scan_c<<<(N+255)/256,256,0,stream>>>(rowptr, blocksum, N);
  k_fill<<<1024,256,0,stream>>>(ei, E, Etot, rowptr, cursor, csr_src);
  k_node1f<<<(N+3)/4, 256, 0, stream>>>(rowptr, csr_src, xl1, xr1, att1, b1, Wl2, Wr2, xl2, xr2, N);
  k_node2<<<(N+3)/4, 256, 0, stream>>>(rowptr, csr_src, xl2, xr2, att2, b2, (float*)d_out, N);
}

// Round 5
// 174.258 us; speedup vs baseline: 3.2789x; 1.2046x over previous
//
#include <hip/hip_runtime.h>
#include <math.h>

#define FIN 128
#define H 64
#define FOUT 2
#define NEG_SLOPE 0.2f
#define EPS 1e-16f
#define MNEG -1e30f

#define BM 128
#define BK 32
#define SCAN_CHUNK 2048   // elements per scan_a block (256 thr * 8)

__device__ __forceinline__ float waveSum(float v){
  #pragma unroll
  for(int o=1;o<64;o<<=1) v += __shfl_xor(v,o);
  return v;
}
__device__ __forceinline__ float waveMax(float v){
  #pragma unroll
  for(int o=1;o<64;o<<=1) v = fmaxf(v, __shfl_xor(v,o));
  return v;
}

// K0: zero int buffer
__global__ void k_zero_int(int* __restrict__ a, int n){
  int i = blockIdx.x*blockDim.x + threadIdx.x;
  int stride = gridDim.x*blockDim.x;
  for(; i<n; i+=stride) a[i]=0;
}

// K1: [N,128] @ [128, 64|64] -> xl, xr.  LDS-tiled, 8x8 register micro-tile.
__global__ __launch_bounds__(256) void k_gemm1(
    const float* __restrict__ x, const float* __restrict__ Wl,
    const float* __restrict__ Wr, float* __restrict__ xl,
    float* __restrict__ xr, int N){
  __shared__ float xsT[BK][BM+4];
  __shared__ float ws[BK][128];
  int tid = threadIdx.x;
  int rowbase = blockIdx.x*BM;
  int tc = tid & 15, tr = tid >> 4;
  int r0 = tr*8, c0 = tc*4;
  float acc[8][8];
  #pragma unroll
  for(int i=0;i<8;i++)
    #pragma unroll
    for(int j=0;j<8;j++) acc[i][j]=0.f;

  int lrow = tid >> 1;
  int lk16 = (tid & 1) * 16;
  int wkk  = tid >> 3;
  int wfq  = tid & 7;

  for(int k0=0; k0<FIN; k0+=BK){
    __syncthreads();
    {
      int grow = rowbase + lrow;
      #pragma unroll
      for(int q=0;q<2;q++){
        int kc = lk16 + q*8;
        float4 v0 = make_float4(0,0,0,0), v1 = make_float4(0,0,0,0);
        if(grow < N){
          v0 = *(const float4*)(x + (size_t)grow*FIN + k0 + kc);
          v1 = *(const float4*)(x + (size_t)grow*FIN + k0 + kc + 4);
        }
        xsT[kc+0][lrow]=v0.x; xsT[kc+1][lrow]=v0.y; xsT[kc+2][lrow]=v0.z; xsT[kc+3][lrow]=v0.w;
        xsT[kc+4][lrow]=v1.x; xsT[kc+5][lrow]=v1.y; xsT[kc+6][lrow]=v1.z; xsT[kc+7][lrow]=v1.w;
      }
    }
    #pragma unroll
    for(int i=0;i<4;i++){
      int c4 = (wfq + i*8)*4;
      const float* srcp = (c4 < 64) ? (Wl + (size_t)(k0+wkk)*H + c4)
                                    : (Wr + (size_t)(k0+wkk)*H + (c4-64));
      *(float4*)(&ws[wkk][c4]) = *(const float4*)srcp;
    }
    __syncthreads();
    #pragma unroll
    for(int kk=0; kk<BK; kk++){
      float4 a0 = *(float4*)(&xsT[kk][r0]);
      float4 a1 = *(float4*)(&xsT[kk][r0+4]);
      float4 b0 = *(float4*)(&ws[kk][c0]);
      float4 b1 = *(float4*)(&ws[kk][64+c0]);
      float a[8] = {a0.x,a0.y,a0.z,a0.w,a1.x,a1.y,a1.z,a1.w};
      float b[8] = {b0.x,b0.y,b0.z,b0.w,b1.x,b1.y,b1.z,b1.w};
      #pragma unroll
      for(int i=0;i<8;i++)
        #pragma unroll
        for(int j=0;j<8;j++)
          acc[i][j] += a[i]*b[j];
    }
  }
  #pragma unroll
  for(int i=0;i<8;i++){
    int row = rowbase + r0 + i;
    if(row < N){
      *(float4*)(xl + (size_t)row*H + c0) = make_float4(acc[i][0],acc[i][1],acc[i][2],acc[i][3]);
      *(float4*)(xr + (size_t)row*H + c0) = make_float4(acc[i][4],acc[i][5],acc[i][6],acc[i][7]);
    }
  }
}

// K2: degree count + per-edge rank (uses the atomic's return value; coalesced rank write)
__global__ void k_degree(const int* __restrict__ ei, int E, int Etot,
                         int* __restrict__ deg, int* __restrict__ rank){
  int i0 = (blockIdx.x*blockDim.x + threadIdx.x)*4;
  if(i0 >= Etot) return;
  if(i0 + 4 <= E && (E & 3) == 0){
    int4 d4 = *(const int4*)(ei + E + i0);
    int r0 = atomicAdd(&deg[d4.x],1);
    int r1 = atomicAdd(&deg[d4.y],1);
    int r2 = atomicAdd(&deg[d4.z],1);
    int r3 = atomicAdd(&deg[d4.w],1);
    *(int4*)(rank + i0) = make_int4(r0,r1,r2,r3);
  } else if(i0 >= E && i0 + 4 <= Etot){
    int v = i0 - E;
    int r0 = atomicAdd(&deg[v+0],1);
    int r1 = atomicAdd(&deg[v+1],1);
    int r2 = atomicAdd(&deg[v+2],1);
    int r3 = atomicAdd(&deg[v+3],1);
    *(int4*)(rank + i0) = make_int4(r0,r1,r2,r3);
  } else {
    #pragma unroll
    for(int q=0;q<4;q++){
      int i = i0+q; if(i>=Etot) break;
      int dst = (i<E) ? ei[E+i] : (i-E);
      rank[i] = atomicAdd(&deg[dst],1);
    }
  }
}

// K3a: per-block scan of deg (2048 elems/block), local-exclusive into rowptr, block totals
__global__ __launch_bounds__(256) void k_scan_a(const int* __restrict__ deg, int n,
                                                int* __restrict__ rowptr,
                                                int* __restrict__ blocksum){
  __shared__ int wsum[4];
  int tid = threadIdx.x, lane = tid & 63, wid = tid >> 6;
  int idx = blockIdx.x*SCAN_CHUNK + tid*8;
  int v[8];
  if(idx + 8 <= n){
    int4 a = *(const int4*)(deg + idx);
    int4 b = *(const int4*)(deg + idx + 4);
    v[0]=a.x;v[1]=a.y;v[2]=a.z;v[3]=a.w;v[4]=b.x;v[5]=b.y;v[6]=b.z;v[7]=b.w;
  } else {
    #pragma unroll
    for(int i=0;i<8;i++) v[i] = (idx+i<n)? deg[idx+i] : 0;
  }
  int pre[8]; int st=0;
  #pragma unroll
  for(int i=0;i<8;i++){ pre[i]=st; st+=v[i]; }
  int incl = st;
  #pragma unroll
  for(int o=1;o<64;o<<=1){ int u=__shfl_up(incl,o); if(lane>=o) incl+=u; }
  if(lane==63) wsum[wid]=incl;
  __syncthreads();
  if(tid==0){ int accu=0; for(int i=0;i<4;i++){ int t=wsum[i]; wsum[i]=accu; accu+=t; } }
  __syncthreads();
  int toff = wsum[wid] + incl - st;
  if(idx + 8 <= n){
    int4 o0 = make_int4(toff+pre[0],toff+pre[1],toff+pre[2],toff+pre[3]);
    int4 o1 = make_int4(toff+pre[4],toff+pre[5],toff+pre[6],toff+pre[7]);
    *(int4*)(rowptr+idx)=o0; *(int4*)(rowptr+idx+4)=o1;
  } else {
    #pragma unroll
    for(int i=0;i<8;i++) if(idx+i<n) rowptr[idx+i]=toff+pre[i];
  }
  if(tid==255) blocksum[blockIdx.x] = toff + st;
}

// K3b: exclusive scan of block sums (nb <= 64), total -> rowptr[n]
__global__ void k_scan_b(int* __restrict__ blocksum, int nb, int* __restrict__ rowptr, int n){
  int lane = threadIdx.x & 63;
  int v = (lane<nb)? blocksum[lane] : 0;
  int incl = v;
  #pragma unroll
  for(int o=1;o<64;o<<=1){ int u=__shfl_up(incl,o); if(lane>=o) incl+=u; }
  if(lane<nb) blocksum[lane] = incl - v;
  if(lane==63) rowptr[n] = incl;
}

// K3c: add block offsets
__global__ void k_scan_c(int* __restrict__ rowptr, const int* __restrict__ blocksum, int n){
  int i = blockIdx.x*blockDim.x + threadIdx.x;
  if(i<n) rowptr[i] += blocksum[i >> 11];  // SCAN_CHUNK = 2048
}

// K4: CSR fill — no atomics; p = rowptr[dst] + rank[i]; 4-wide MLP
__global__ void k_fill(const int* __restrict__ ei, int E, int Etot,
                       const int* __restrict__ rowptr,
                       const int* __restrict__ rank, int* __restrict__ csr_src){
  int i0 = (blockIdx.x*blockDim.x + threadIdx.x)*4;
  if(i0 >= Etot) return;
  if(i0 + 4 <= E && (E & 3) == 0){
    int4 s4 = *(const int4*)(ei + i0);
    int4 d4 = *(const int4*)(ei + E + i0);
    int4 r4 = *(const int4*)(rank + i0);
    csr_src[rowptr[d4.x] + r4.x] = s4.x;
    csr_src[rowptr[d4.y] + r4.y] = s4.y;
    csr_src[rowptr[d4.z] + r4.z] = s4.z;
    csr_src[rowptr[d4.w] + r4.w] = s4.w;
  } else if(i0 >= E && i0 + 4 <= Etot){
    int4 r4 = *(const int4*)(rank + i0);
    int v = i0 - E;
    csr_src[rowptr[v+0] + r4.x] = v+0;
    csr_src[rowptr[v+1] + r4.y] = v+1;
    csr_src[rowptr[v+2] + r4.z] = v+2;
    csr_src[rowptr[v+3] + r4.w] = v+3;
  } else {
    #pragma unroll
    for(int q=0;q<4;q++){
      int i = i0+q; if(i>=Etot) break;
      int src, dst;
      if(i<E){ src = ei[i]; dst = ei[E+i]; } else { src = i-E; dst = i-E; }
      csr_src[rowptr[dst] + rank[i]] = src;
    }
  }
}

// K5: fused layer-1: edge logits + online softmax + aggregate + layer-2 projection.
__global__ void k_node1f(const int* __restrict__ rowptr, const int* __restrict__ csr_src,
                         const float* __restrict__ xl, const float* __restrict__ xr,
                         const float* __restrict__ att, const float* __restrict__ b1,
                         const float* __restrict__ Wl2, const float* __restrict__ Wr2,
                         float* __restrict__ xl2, float* __restrict__ xr2, int N){
  int node = blockIdx.x*4 + (threadIdx.x>>6);
  int lane = threadIdx.x & 63;
  if(node >= N) return;
  int g  = lane >> 4;
  int f4 = (lane & 15) * 4;
  float4 attv = *(const float4*)(att + f4);
  float4 xrv  = *(const float4*)(xr + (size_t)node*H + f4);
  int s = rowptr[node], t = rowptr[node+1];
  float m = MNEG, d = 0.f;
  float ax=0.f, ay=0.f, az=0.f, aw=0.f;
  for(int k = s + g; k < t; k += 4){
    int src = csr_src[k];
    float4 xv = *(const float4*)(xl + (size_t)src*H + f4);
    float h0 = xv.x + xrv.x, h1 = xv.y + xrv.y, h2 = xv.z + xrv.z, h3 = xv.w + xrv.w;
    float l0 = (h0>0.f)? h0 : NEG_SLOPE*h0;
    float l1 = (h1>0.f)? h1 : NEG_SLOPE*h1;
    float l2 = (h2>0.f)? h2 : NEG_SLOPE*h2;
    float l3 = (h3>0.f)? h3 : NEG_SLOPE*h3;
    float e = l0*attv.x + l1*attv.y + l2*attv.z + l3*attv.w;
    #pragma unroll
    for(int o=1;o<16;o<<=1) e += __shfl_xor(e,o);
    float M  = fmaxf(m, e);
    float sc = __expf(m - M);
    float w  = __expf(e - M);
    d  = d*sc + w;
    ax = ax*sc + w*xv.x; ay = ay*sc + w*xv.y;
    az = az*sc + w*xv.z; aw = aw*sc + w*xv.w;
    m = M;
  }
  #pragma unroll
  for(int o=16;o<64;o<<=1){
    float m2 = __shfl_xor(m,o);
    float d2 = __shfl_xor(d,o);
    float bx = __shfl_xor(ax,o), by = __shfl_xor(ay,o);
    float bz = __shfl_xor(az,o), bw = __shfl_xor(aw,o);
    float M  = fmaxf(m, m2);
    float s1 = __expf(m - M), s2 = __expf(m2 - M);
    d  = d*s1 + d2*s2;
    ax = ax*s1 + bx*s2; ay = ay*s1 + by*s2;
    az = az*s1 + bz*s2; aw = aw*s1 + bw*s2;
    m = M;
  }
  float inv = 1.f/(d + EPS);
  float4 bv = *(const float4*)(b1 + f4);
  float h0 = ax*inv + bv.x, h1 = ay*inv + bv.y;
  float h2 = az*inv + bv.z, h3 = aw*inv + bv.w;
  const float* Wp = (g<2) ? Wl2 : Wr2;
  int col = g & 1;
  float p = h0*Wp[(f4+0)*FOUT+col] + h1*Wp[(f4+1)*FOUT+col]
          + h2*Wp[(f4+2)*FOUT+col] + h3*Wp[(f4+3)*FOUT+col];
  #pragma unroll
  for(int o=1;o<16;o<<=1) p += __shfl_xor(p,o);
  if((lane&15)==0){
    if(g==0)      xl2[node*2+0]=p;
    else if(g==1) xl2[node*2+1]=p;
    else if(g==2) xr2[node*2+0]=p;
    else          xr2[node*2+1]=p;
  }
}

// K7: layer-2 full conv (logit recompute inline, F=2)
__global__ void k_node2(const int* __restrict__ rowptr, const int* __restrict__ csr_src,
                        const float* __restrict__ xl2, const float* __restrict__ xr2,
                        const float* __restrict__ att2, const float* __restrict__ b2,
                        float* __restrict__ out, int N){
  int node = blockIdx.x*4 + (threadIdx.x>>6);
  int lane = threadIdx.x & 63;
  if(node >= N) return;
  int s = rowptr[node], t = rowptr[node+1];
  float xr0 = xr2[node*2+0], xr1v = xr2[node*2+1];
  float a0 = att2[0], a1 = att2[1];
  float m = MNEG;
  for(int k=s+lane; k<t; k+=64){
    int src = csr_src[k];
    float h0 = xl2[src*2+0] + xr0, h1 = xl2[src*2+1] + xr1v;
    h0 = (h0>0.f)? h0 : NEG_SLOPE*h0;
    h1 = (h1>0.f)? h1 : NEG_SLOPE*h1;
    m = fmaxf(m, h0*a0 + h1*a1);
  }
  m = waveMax(m);
  float den=0.f, n0=0.f, n1=0.f;
  for(int k=s+lane; k<t; k+=64){
    int src = csr_src[k];
    float xs0 = xl2[src*2+0], xs1 = xl2[src*2+1];
    float h0 = xs0 + xr0, h1 = xs1 + xr1v;
    float l0 = (h0>0.f)? h0 : NEG_SLOPE*h0;
    float l1 = (h1>0.f)? h1 : NEG_SLOPE*h1;
    float ex = __expf(l0*a0 + l1*a1 - m);
    den += ex; n0 += ex*xs0; n1 += ex*xs1;
  }
  den = waveSum(den); n0 = waveSum(n0); n1 = waveSum(n1);
  if(lane==0){
    float inv = 1.f/(den + EPS);
    out[node*2+0] = n0*inv + b2[0];
    out[node*2+1] = n1*inv + b2[1];
  }
}

extern "C" void kernel_launch(void* const* d_in, const int* in_sizes, int n_in,
                              void* d_out, int out_size, void* d_ws, size_t ws_size,
                              hipStream_t stream){
  const float* x    = (const float*)d_in[0];
  const int*   ei   = (const int*)d_in[1];
  const float* Wl1  = (const float*)d_in[2];
  const float* Wr1  = (const float*)d_in[3];
  const float* att1 = (const float*)d_in[4];
  const float* b1   = (const float*)d_in[5];
  const float* Wl2  = (const float*)d_in[6];
  const float* Wr2  = (const float*)d_in[7];
  const float* att2 = (const float*)d_in[8];
  const float* b2   = (const float*)d_in[9];
  int N = in_sizes[0]/FIN;
  int E = in_sizes[1]/2;
  int Etot = E + N;
  int nscan = (N + SCAN_CHUNK - 1) / SCAN_CHUNK;   // 25 for N=50000 (<=64 supported)
  int nquad = (Etot + 3) / 4;                       // 4-edge packages

  char* w = (char*)d_ws;
  size_t off = 0;
  auto alloc = [&](size_t bytes)->void*{
    void* p = w + off;
    off = (off + bytes + 255) & ~(size_t)255;
    return p;
  };
  float* xl1     = (float*)alloc((size_t)N*H*4);
  float* xr1     = (float*)alloc((size_t)N*H*4);
  int*   csr_src = (int*)  alloc((size_t)Etot*4);
  int*   rank    = (int*)  alloc((size_t)Etot*4);
  int*   deg     = (int*)  alloc((size_t)N*4);
  int*   rowptr  = (int*)  alloc((size_t)(N+1)*4);
  int*   blocksum= (int*)  alloc((size_t)64*4);
  float* xl2     = (float*)alloc((size_t)N*2*4);
  float* xr2     = (float*)alloc((size_t)N*2*4);

  k_zero_int<<<128,256,0,stream>>>(deg, N);
  k_gemm1<<<(N+BM-1)/BM, 256, 0, stream>>>(x, Wl1, Wr1, xl1, xr1, N);
  k_degree<<<(nquad+255)/256,256,0,stream>>>(ei, E, Etot, deg, rank);
  k_scan_a<<<nscan,256,0,stream>>>(deg, N, rowptr, blocksum);
  k_scan_b<<<1,64,0,stream>>>(blocksum, nscan, rowptr, N);
  k_scan_c<<<(N+255)/256,256,0,stream>>>(rowptr, blocksum, N);
  k_fill<<<(nquad+255)/256,256,0,stream>>>(ei, E, Etot, rowptr, rank, csr_src);
  k_node1f<<<(N+3)/4, 256, 0, stream>>>(rowptr, csr_src, xl1, xr1, att1, b1, Wl2, Wr2, xl2, xr2, N);
  k_node2<<<(N+3)/4, 256, 0, stream>>>(rowptr, csr_src, xl2, xr2, att2, b2, (float*)d_out, N);
}

// Round 6
// 158.302 us; speedup vs baseline: 3.6094x; 1.1008x over previous
//
#include <hip/hip_runtime.h>
#include <math.h>

#define FIN 128
#define H 64
#define FOUT 2
#define NEG_SLOPE 0.2f
#define EPS 1e-16f

#define BM 128
#define BK 32
#define SCAN_CHUNK 2048   // elements per scan_a block (256 thr * 8)

// K1: [N,128] @ [128, 64|64] -> xl, xr.  LDS-tiled, 8x8 register micro-tile.
__global__ __launch_bounds__(256) void k_gemm1(
    const float* __restrict__ x, const float* __restrict__ Wl,
    const float* __restrict__ Wr, float* __restrict__ xl,
    float* __restrict__ xr, int N){
  __shared__ float xsT[BK][BM+4];
  __shared__ float ws[BK][128];
  int tid = threadIdx.x;
  int rowbase = blockIdx.x*BM;
  int tc = tid & 15, tr = tid >> 4;
  int r0 = tr*8, c0 = tc*4;
  float acc[8][8];
  #pragma unroll
  for(int i=0;i<8;i++)
    #pragma unroll
    for(int j=0;j<8;j++) acc[i][j]=0.f;

  int lrow = tid >> 1;
  int lk16 = (tid & 1) * 16;
  int wkk  = tid >> 3;
  int wfq  = tid & 7;

  for(int k0=0; k0<FIN; k0+=BK){
    __syncthreads();
    {
      int grow = rowbase + lrow;
      #pragma unroll
      for(int q=0;q<2;q++){
        int kc = lk16 + q*8;
        float4 v0 = make_float4(0,0,0,0), v1 = make_float4(0,0,0,0);
        if(grow < N){
          v0 = *(const float4*)(x + (size_t)grow*FIN + k0 + kc);
          v1 = *(const float4*)(x + (size_t)grow*FIN + k0 + kc + 4);
        }
        xsT[kc+0][lrow]=v0.x; xsT[kc+1][lrow]=v0.y; xsT[kc+2][lrow]=v0.z; xsT[kc+3][lrow]=v0.w;
        xsT[kc+4][lrow]=v1.x; xsT[kc+5][lrow]=v1.y; xsT[kc+6][lrow]=v1.z; xsT[kc+7][lrow]=v1.w;
      }
    }
    #pragma unroll
    for(int i=0;i<4;i++){
      int c4 = (wfq + i*8)*4;
      const float* srcp = (c4 < 64) ? (Wl + (size_t)(k0+wkk)*H + c4)
                                    : (Wr + (size_t)(k0+wkk)*H + (c4-64));
      *(float4*)(&ws[wkk][c4]) = *(const float4*)srcp;
    }
    __syncthreads();
    #pragma unroll
    for(int kk=0; kk<BK; kk++){
      float4 a0 = *(float4*)(&xsT[kk][r0]);
      float4 a1 = *(float4*)(&xsT[kk][r0+4]);
      float4 b0 = *(float4*)(&ws[kk][c0]);
      float4 b1 = *(float4*)(&ws[kk][64+c0]);
      float a[8] = {a0.x,a0.y,a0.z,a0.w,a1.x,a1.y,a1.z,a1.w};
      float b[8] = {b0.x,b0.y,b0.z,b0.w,b1.x,b1.y,b1.z,b1.w};
      #pragma unroll
      for(int i=0;i<8;i++)
        #pragma unroll
        for(int j=0;j<8;j++)
          acc[i][j] += a[i]*b[j];
    }
  }
  #pragma unroll
  for(int i=0;i<8;i++){
    int row = rowbase + r0 + i;
    if(row < N){
      *(float4*)(xl + (size_t)row*H + c0) = make_float4(acc[i][0],acc[i][1],acc[i][2],acc[i][3]);
      *(float4*)(xr + (size_t)row*H + c0) = make_float4(acc[i][4],acc[i][5],acc[i][6],acc[i][7]);
    }
  }
}

// K2: degree count + per-edge rank (uses the atomic's return value; coalesced rank write)
__global__ void k_degree(const int* __restrict__ ei, int E, int Etot,
                         int* __restrict__ deg, int* __restrict__ rank){
  int i0 = (blockIdx.x*blockDim.x + threadIdx.x)*4;
  if(i0 >= Etot) return;
  if(i0 + 4 <= E && (E & 3) == 0){
    int4 d4 = *(const int4*)(ei + E + i0);
    int r0 = atomicAdd(&deg[d4.x],1);
    int r1 = atomicAdd(&deg[d4.y],1);
    int r2 = atomicAdd(&deg[d4.z],1);
    int r3 = atomicAdd(&deg[d4.w],1);
    *(int4*)(rank + i0) = make_int4(r0,r1,r2,r3);
  } else if(i0 >= E && i0 + 4 <= Etot){
    int v = i0 - E;
    int r0 = atomicAdd(&deg[v+0],1);
    int r1 = atomicAdd(&deg[v+1],1);
    int r2 = atomicAdd(&deg[v+2],1);
    int r3 = atomicAdd(&deg[v+3],1);
    *(int4*)(rank + i0) = make_int4(r0,r1,r2,r3);
  } else {
    #pragma unroll
    for(int q=0;q<4;q++){
      int i = i0+q; if(i>=Etot) break;
      int dst = (i<E) ? ei[E+i] : (i-E);
      rank[i] = atomicAdd(&deg[dst],1);
    }
  }
}

// K3a: per-block scan of deg (2048 elems/block), local-exclusive into rowptr, block totals
__global__ __launch_bounds__(256) void k_scan_a(const int* __restrict__ deg, int n,
                                                int* __restrict__ rowptr,
                                                int* __restrict__ blocksum){
  __shared__ int wsum[4];
  int tid = threadIdx.x, lane = tid & 63, wid = tid >> 6;
  int idx = blockIdx.x*SCAN_CHUNK + tid*8;
  int v[8];
  if(idx + 8 <= n){
    int4 a = *(const int4*)(deg + idx);
    int4 b = *(const int4*)(deg + idx + 4);
    v[0]=a.x;v[1]=a.y;v[2]=a.z;v[3]=a.w;v[4]=b.x;v[5]=b.y;v[6]=b.z;v[7]=b.w;
  } else {
    #pragma unroll
    for(int i=0;i<8;i++) v[i] = (idx+i<n)? deg[idx+i] : 0;
  }
  int pre[8]; int st=0;
  #pragma unroll
  for(int i=0;i<8;i++){ pre[i]=st; st+=v[i]; }
  int incl = st;
  #pragma unroll
  for(int o=1;o<64;o<<=1){ int u=__shfl_up(incl,o); if(lane>=o) incl+=u; }
  if(lane==63) wsum[wid]=incl;
  __syncthreads();
  if(tid==0){ int accu=0; for(int i=0;i<4;i++){ int t=wsum[i]; wsum[i]=accu; accu+=t; } }
  __syncthreads();
  int toff = wsum[wid] + incl - st;
  if(idx + 8 <= n){
    int4 o0 = make_int4(toff+pre[0],toff+pre[1],toff+pre[2],toff+pre[3]);
    int4 o1 = make_int4(toff+pre[4],toff+pre[5],toff+pre[6],toff+pre[7]);
    *(int4*)(rowptr+idx)=o0; *(int4*)(rowptr+idx+4)=o1;
  } else {
    #pragma unroll
    for(int i=0;i<8;i++) if(idx+i<n) rowptr[idx+i]=toff+pre[i];
  }
  if(tid==255) blocksum[blockIdx.x] = toff + st;
}

// K3b: exclusive scan of block sums (nb <= 64), total -> rowptr[n]
__global__ void k_scan_b(int* __restrict__ blocksum, int nb, int* __restrict__ rowptr, int n){
  int lane = threadIdx.x & 63;
  int v = (lane<nb)? blocksum[lane] : 0;
  int incl = v;
  #pragma unroll
  for(int o=1;o<64;o<<=1){ int u=__shfl_up(incl,o); if(lane>=o) incl+=u; }
  if(lane<nb) blocksum[lane] = incl - v;
  if(lane==63) rowptr[n] = incl;
}

// K3c: add block offsets
__global__ void k_scan_c(int* __restrict__ rowptr, const int* __restrict__ blocksum, int n){
  int i = blockIdx.x*blockDim.x + threadIdx.x;
  if(i<n) rowptr[i] += blocksum[i >> 11];  // SCAN_CHUNK = 2048
}

// K4: CSR fill — no atomics; p = rowptr[dst] + rank[i]; 4-wide MLP
__global__ void k_fill(const int* __restrict__ ei, int E, int Etot,
                       const int* __restrict__ rowptr,
                       const int* __restrict__ rank, int* __restrict__ csr_src){
  int i0 = (blockIdx.x*blockDim.x + threadIdx.x)*4;
  if(i0 >= Etot) return;
  if(i0 + 4 <= E && (E & 3) == 0){
    int4 s4 = *(const int4*)(ei + i0);
    int4 d4 = *(const int4*)(ei + E + i0);
    int4 r4 = *(const int4*)(rank + i0);
    csr_src[rowptr[d4.x] + r4.x] = s4.x;
    csr_src[rowptr[d4.y] + r4.y] = s4.y;
    csr_src[rowptr[d4.z] + r4.z] = s4.z;
    csr_src[rowptr[d4.w] + r4.w] = s4.w;
  } else if(i0 >= E && i0 + 4 <= Etot){
    int4 r4 = *(const int4*)(rank + i0);
    int v = i0 - E;
    csr_src[rowptr[v+0] + r4.x] = v+0;
    csr_src[rowptr[v+1] + r4.y] = v+1;
    csr_src[rowptr[v+2] + r4.z] = v+2;
    csr_src[rowptr[v+3] + r4.w] = v+3;
  } else {
    #pragma unroll
    for(int q=0;q<4;q++){
      int i = i0+q; if(i>=Etot) break;
      int src, dst;
      if(i<E){ src = ei[i]; dst = ei[E+i]; } else { src = i-E; dst = i-E; }
      csr_src[rowptr[dst] + rank[i]] = src;
    }
  }
}

// K5: fused layer-1: edge logits + softmax (no-max: logits bounded, exp safe in fp32)
// + aggregate + layer-2 projection.  One wave/node; 4 groups x 16 lanes;
// group processes one edge/iter with 1-deep gather prefetch; lane = 4 features.
__global__ void k_node1f(const int* __restrict__ rowptr, const int* __restrict__ csr_src,
                         const float* __restrict__ xl, const float* __restrict__ xr,
                         const float* __restrict__ att, const float* __restrict__ b1,
                         const float* __restrict__ Wl2, const float* __restrict__ Wr2,
                         float* __restrict__ xl2, float* __restrict__ xr2, int N){
  int node = blockIdx.x*4 + (threadIdx.x>>6);
  int lane = threadIdx.x & 63;
  if(node >= N) return;
  int g  = lane >> 4;
  int f4 = (lane & 15) * 4;
  float4 attv = *(const float4*)(att + f4);
  float4 xrv  = *(const float4*)(xr + (size_t)node*H + f4);
  int s = rowptr[node], t = rowptr[node+1];
  float d = 0.f;
  float ax=0.f, ay=0.f, az=0.f, aw=0.f;
  int k = s + g;
  float4 xvn = make_float4(0,0,0,0);
  if(k < t){
    int srcn = csr_src[k];
    xvn = *(const float4*)(xl + (size_t)srcn*H + f4);
  }
  while(k < t){
    float4 xv = xvn;
    int k2 = k + 4;
    if(k2 < t){                                   // prefetch next edge's gather
      int srcn = csr_src[k2];
      xvn = *(const float4*)(xl + (size_t)srcn*H + f4);
    }
    float h0 = xv.x + xrv.x, h1 = xv.y + xrv.y, h2 = xv.z + xrv.z, h3 = xv.w + xrv.w;
    float l0 = (h0>0.f)? h0 : NEG_SLOPE*h0;
    float l1 = (h1>0.f)? h1 : NEG_SLOPE*h1;
    float l2 = (h2>0.f)? h2 : NEG_SLOPE*h2;
    float l3 = (h3>0.f)? h3 : NEG_SLOPE*h3;
    float e = l0*attv.x + l1*attv.y + l2*attv.z + l3*attv.w;
    #pragma unroll
    for(int o=1;o<16;o<<=1) e += __shfl_xor(e,o);
    float w = __expf(e);
    d  += w;
    ax += w*xv.x; ay += w*xv.y; az += w*xv.z; aw += w*xv.w;
    k = k2;
  }
  // merge 4 group partials (plain sums)
  #pragma unroll
  for(int o=16;o<64;o<<=1){
    d  += __shfl_xor(d,o);
    ax += __shfl_xor(ax,o); ay += __shfl_xor(ay,o);
    az += __shfl_xor(az,o); aw += __shfl_xor(aw,o);
  }
  float inv = 1.f/(d + EPS);
  float4 bv = *(const float4*)(b1 + f4);
  float h0 = ax*inv + bv.x, h1 = ay*inv + bv.y;
  float h2 = az*inv + bv.z, h3 = aw*inv + bv.w;
  const float* Wp = (g<2) ? Wl2 : Wr2;
  int col = g & 1;
  float p = h0*Wp[(f4+0)*FOUT+col] + h1*Wp[(f4+1)*FOUT+col]
          + h2*Wp[(f4+2)*FOUT+col] + h3*Wp[(f4+3)*FOUT+col];
  #pragma unroll
  for(int o=1;o<16;o<<=1) p += __shfl_xor(p,o);
  if((lane&15)==0){
    if(g==0)      xl2[node*2+0]=p;
    else if(g==1) xl2[node*2+1]=p;
    else if(g==2) xr2[node*2+0]=p;
    else          xr2[node*2+1]=p;
  }
}

// K7: layer-2 full conv, single pass (no-max), 16-lane group per node, 4 nodes/wave
__global__ void k_node2(const int* __restrict__ rowptr, const int* __restrict__ csr_src,
                        const float* __restrict__ xl2, const float* __restrict__ xr2,
                        const float* __restrict__ att2, const float* __restrict__ b2,
                        float* __restrict__ out, int N){
  int node = blockIdx.x*16 + (threadIdx.x>>4);
  int gl = threadIdx.x & 15;
  if(node >= N) return;
  int s = rowptr[node], t = rowptr[node+1];
  float2 xrv = *(const float2*)(xr2 + node*2);
  float a0 = att2[0], a1 = att2[1];
  float den=0.f, n0=0.f, n1=0.f;
  for(int k=s+gl; k<t; k+=16){
    int src = csr_src[k];
    float2 xs = *(const float2*)(xl2 + src*2);
    float h0 = xs.x + xrv.x, h1 = xs.y + xrv.y;
    float l0 = (h0>0.f)? h0 : NEG_SLOPE*h0;
    float l1 = (h1>0.f)? h1 : NEG_SLOPE*h1;
    float ex = __expf(l0*a0 + l1*a1);
    den += ex; n0 += ex*xs.x; n1 += ex*xs.y;
  }
  #pragma unroll
  for(int o=1;o<16;o<<=1){
    den += __shfl_xor(den,o);
    n0  += __shfl_xor(n0,o);
    n1  += __shfl_xor(n1,o);
  }
  if(gl==0){
    float inv = 1.f/(den + EPS);
    out[node*2+0] = n0*inv + b2[0];
    out[node*2+1] = n1*inv + b2[1];
  }
}

extern "C" void kernel_launch(void* const* d_in, const int* in_sizes, int n_in,
                              void* d_out, int out_size, void* d_ws, size_t ws_size,
                              hipStream_t stream){
  const float* x    = (const float*)d_in[0];
  const int*   ei   = (const int*)d_in[1];
  const float* Wl1  = (const float*)d_in[2];
  const float* Wr1  = (const float*)d_in[3];
  const float* att1 = (const float*)d_in[4];
  const float* b1   = (const float*)d_in[5];
  const float* Wl2  = (const float*)d_in[6];
  const float* Wr2  = (const float*)d_in[7];
  const float* att2 = (const float*)d_in[8];
  const float* b2   = (const float*)d_in[9];
  int N = in_sizes[0]/FIN;
  int E = in_sizes[1]/2;
  int Etot = E + N;
  int nscan = (N + SCAN_CHUNK - 1) / SCAN_CHUNK;   // 25 for N=50000 (<=64 supported)
  int nquad = (Etot + 3) / 4;                       // 4-edge packages

  char* w = (char*)d_ws;
  size_t off = 0;
  auto alloc = [&](size_t bytes)->void*{
    void* p = w + off;
    off = (off + bytes + 255) & ~(size_t)255;
    return p;
  };
  float* xl1     = (float*)alloc((size_t)N*H*4);
  float* xr1     = (float*)alloc((size_t)N*H*4);
  int*   csr_src = (int*)  alloc((size_t)Etot*4);
  int*   rank    = (int*)  alloc((size_t)Etot*4);
  int*   deg     = (int*)  alloc((size_t)N*4);
  int*   rowptr  = (int*)  alloc((size_t)(N+1)*4);
  int*   blocksum= (int*)  alloc((size_t)64*4);
  float* xl2     = (float*)alloc((size_t)N*2*4);
  float* xr2     = (float*)alloc((size_t)N*2*4);

  hipMemsetAsync(deg, 0, (size_t)N*4, stream);
  k_gemm1<<<(N+BM-1)/BM, 256, 0, stream>>>(x, Wl1, Wr1, xl1, xr1, N);
  k_degree<<<(nquad+255)/256,256,0,stream>>>(ei, E, Etot, deg, rank);
  k_scan_a<<<nscan,256,0,stream>>>(deg, N, rowptr, blocksum);
  k_scan_b<<<1,64,0,stream>>>(blocksum, nscan, rowptr, N);
  k_scan_c<<<(N+255)/256,256,0,stream>>>(rowptr, blocksum, N);
  k_fill<<<(nquad+255)/256,256,0,stream>>>(ei, E, Etot, rowptr, rank, csr_src);
  k_node1f<<<(N+3)/4, 256, 0, stream>>>(rowptr, csr_src, xl1, xr1, att1, b1, Wl2, Wr2, xl2, xr2, N);
  k_node2<<<(N+15)/16, 256, 0, stream>>>(rowptr, csr_src, xl2, xr2, att2, b2, (float*)d_out, N);
}

// Round 7
// 142.955 us; speedup vs baseline: 3.9969x; 1.1074x over previous
//
#include <hip/hip_runtime.h>
#include <math.h>

#define FIN 128
#define H 64
#define FOUT 2
#define NEG_SLOPE 0.2f
#define EPS 1e-16f

#define BM 128
#define BK 32
#define SCAN_CHUNK 2048   // elements per scan_a block (256 thr * 8)

// K1: [N,128] @ [128, 64|64] -> xl, xr.  LDS-tiled, 8x8 register micro-tile.
__global__ __launch_bounds__(256) void k_gemm1(
    const float* __restrict__ x, const float* __restrict__ Wl,
    const float* __restrict__ Wr, float* __restrict__ xl,
    float* __restrict__ xr, int N){
  __shared__ float xsT[BK][BM+4];
  __shared__ float ws[BK][128];
  int tid = threadIdx.x;
  int rowbase = blockIdx.x*BM;
  int tc = tid & 15, tr = tid >> 4;
  int r0 = tr*8, c0 = tc*4;
  float acc[8][8];
  #pragma unroll
  for(int i=0;i<8;i++)
    #pragma unroll
    for(int j=0;j<8;j++) acc[i][j]=0.f;

  int lrow = tid >> 1;
  int lk16 = (tid & 1) * 16;
  int wkk  = tid >> 3;
  int wfq  = tid & 7;

  for(int k0=0; k0<FIN; k0+=BK){
    __syncthreads();
    {
      int grow = rowbase + lrow;
      #pragma unroll
      for(int q=0;q<2;q++){
        int kc = lk16 + q*8;
        float4 v0 = make_float4(0,0,0,0), v1 = make_float4(0,0,0,0);
        if(grow < N){
          v0 = *(const float4*)(x + (size_t)grow*FIN + k0 + kc);
          v1 = *(const float4*)(x + (size_t)grow*FIN + k0 + kc + 4);
        }
        xsT[kc+0][lrow]=v0.x; xsT[kc+1][lrow]=v0.y; xsT[kc+2][lrow]=v0.z; xsT[kc+3][lrow]=v0.w;
        xsT[kc+4][lrow]=v1.x; xsT[kc+5][lrow]=v1.y; xsT[kc+6][lrow]=v1.z; xsT[kc+7][lrow]=v1.w;
      }
    }
    #pragma unroll
    for(int i=0;i<4;i++){
      int c4 = (wfq + i*8)*4;
      const float* srcp = (c4 < 64) ? (Wl + (size_t)(k0+wkk)*H + c4)
                                    : (Wr + (size_t)(k0+wkk)*H + (c4-64));
      *(float4*)(&ws[wkk][c4]) = *(const float4*)srcp;
    }
    __syncthreads();
    #pragma unroll
    for(int kk=0; kk<BK; kk++){
      float4 a0 = *(float4*)(&xsT[kk][r0]);
      float4 a1 = *(float4*)(&xsT[kk][r0+4]);
      float4 b0 = *(float4*)(&ws[kk][c0]);
      float4 b1 = *(float4*)(&ws[kk][64+c0]);
      float a[8] = {a0.x,a0.y,a0.z,a0.w,a1.x,a1.y,a1.z,a1.w};
      float b[8] = {b0.x,b0.y,b0.z,b0.w,b1.x,b1.y,b1.z,b1.w};
      #pragma unroll
      for(int i=0;i<8;i++)
        #pragma unroll
        for(int j=0;j<8;j++)
          acc[i][j] += a[i]*b[j];
    }
  }
  #pragma unroll
  for(int i=0;i<8;i++){
    int row = rowbase + r0 + i;
    if(row < N){
      *(float4*)(xl + (size_t)row*H + c0) = make_float4(acc[i][0],acc[i][1],acc[i][2],acc[i][3]);
      *(float4*)(xr + (size_t)row*H + c0) = make_float4(acc[i][4],acc[i][5],acc[i][6],acc[i][7]);
    }
  }
}

// K2: degree count + per-edge rank (uses the atomic's return value; coalesced rank write)
__global__ void k_degree(const int* __restrict__ ei, int E, int Etot,
                         int* __restrict__ deg, int* __restrict__ rank){
  int i0 = (blockIdx.x*blockDim.x + threadIdx.x)*4;
  if(i0 >= Etot) return;
  if(i0 + 4 <= E && (E & 3) == 0){
    int4 d4 = *(const int4*)(ei + E + i0);
    int r0 = atomicAdd(&deg[d4.x],1);
    int r1 = atomicAdd(&deg[d4.y],1);
    int r2 = atomicAdd(&deg[d4.z],1);
    int r3 = atomicAdd(&deg[d4.w],1);
    *(int4*)(rank + i0) = make_int4(r0,r1,r2,r3);
  } else if(i0 >= E && i0 + 4 <= Etot){
    int v = i0 - E;
    int r0 = atomicAdd(&deg[v+0],1);
    int r1 = atomicAdd(&deg[v+1],1);
    int r2 = atomicAdd(&deg[v+2],1);
    int r3 = atomicAdd(&deg[v+3],1);
    *(int4*)(rank + i0) = make_int4(r0,r1,r2,r3);
  } else {
    #pragma unroll
    for(int q=0;q<4;q++){
      int i = i0+q; if(i>=Etot) break;
      int dst = (i<E) ? ei[E+i] : (i-E);
      rank[i] = atomicAdd(&deg[dst],1);
    }
  }
}

// K3a: per-block scan of deg (2048 elems/block), local-exclusive into rowptr, block totals
__global__ __launch_bounds__(256) void k_scan_a(const int* __restrict__ deg, int n,
                                                int* __restrict__ rowptr,
                                                int* __restrict__ blocksum){
  __shared__ int wsum[4];
  int tid = threadIdx.x, lane = tid & 63, wid = tid >> 6;
  int idx = blockIdx.x*SCAN_CHUNK + tid*8;
  int v[8];
  if(idx + 8 <= n){
    int4 a = *(const int4*)(deg + idx);
    int4 b = *(const int4*)(deg + idx + 4);
    v[0]=a.x;v[1]=a.y;v[2]=a.z;v[3]=a.w;v[4]=b.x;v[5]=b.y;v[6]=b.z;v[7]=b.w;
  } else {
    #pragma unroll
    for(int i=0;i<8;i++) v[i] = (idx+i<n)? deg[idx+i] : 0;
  }
  int pre[8]; int st=0;
  #pragma unroll
  for(int i=0;i<8;i++){ pre[i]=st; st+=v[i]; }
  int incl = st;
  #pragma unroll
  for(int o=1;o<64;o<<=1){ int u=__shfl_up(incl,o); if(lane>=o) incl+=u; }
  if(lane==63) wsum[wid]=incl;
  __syncthreads();
  if(tid==0){ int accu=0; for(int i=0;i<4;i++){ int t=wsum[i]; wsum[i]=accu; accu+=t; } }
  __syncthreads();
  int toff = wsum[wid] + incl - st;
  if(idx + 8 <= n){
    int4 o0 = make_int4(toff+pre[0],toff+pre[1],toff+pre[2],toff+pre[3]);
    int4 o1 = make_int4(toff+pre[4],toff+pre[5],toff+pre[6],toff+pre[7]);
    *(int4*)(rowptr+idx)=o0; *(int4*)(rowptr+idx+4)=o1;
  } else {
    #pragma unroll
    for(int i=0;i<8;i++) if(idx+i<n) rowptr[idx+i]=toff+pre[i];
  }
  if(tid==255) blocksum[blockIdx.x] = toff + st;
}

// K3b: exclusive scan of block sums (nb <= 64), total -> rowptr[n]
__global__ void k_scan_b(int* __restrict__ blocksum, int nb, int* __restrict__ rowptr, int n){
  int lane = threadIdx.x & 63;
  int v = (lane<nb)? blocksum[lane] : 0;
  int incl = v;
  #pragma unroll
  for(int o=1;o<64;o<<=1){ int u=__shfl_up(incl,o); if(lane>=o) incl+=u; }
  if(lane<nb) blocksum[lane] = incl - v;
  if(lane==63) rowptr[n] = incl;
}

// K3c: add block offsets
__global__ void k_scan_c(int* __restrict__ rowptr, const int* __restrict__ blocksum, int n){
  int i = blockIdx.x*blockDim.x + threadIdx.x;
  if(i<n) rowptr[i] += blocksum[i >> 11];  // SCAN_CHUNK = 2048
}

// K4: CSR fill — no atomics; p = rowptr[dst] + rank[i]; 4-wide MLP
__global__ void k_fill(const int* __restrict__ ei, int E, int Etot,
                       const int* __restrict__ rowptr,
                       const int* __restrict__ rank, int* __restrict__ csr_src){
  int i0 = (blockIdx.x*blockDim.x + threadIdx.x)*4;
  if(i0 >= Etot) return;
  if(i0 + 4 <= E && (E & 3) == 0){
    int4 s4 = *(const int4*)(ei + i0);
    int4 d4 = *(const int4*)(ei + E + i0);
    int4 r4 = *(const int4*)(rank + i0);
    csr_src[rowptr[d4.x] + r4.x] = s4.x;
    csr_src[rowptr[d4.y] + r4.y] = s4.y;
    csr_src[rowptr[d4.z] + r4.z] = s4.z;
    csr_src[rowptr[d4.w] + r4.w] = s4.w;
  } else if(i0 >= E && i0 + 4 <= Etot){
    int4 r4 = *(const int4*)(rank + i0);
    int v = i0 - E;
    csr_src[rowptr[v+0] + r4.x] = v+0;
    csr_src[rowptr[v+1] + r4.y] = v+1;
    csr_src[rowptr[v+2] + r4.z] = v+2;
    csr_src[rowptr[v+3] + r4.w] = v+3;
  } else {
    #pragma unroll
    for(int q=0;q<4;q++){
      int i = i0+q; if(i>=Etot) break;
      int src, dst;
      if(i<E){ src = ei[i]; dst = ei[E+i]; } else { src = i-E; dst = i-E; }
      csr_src[rowptr[dst] + rank[i]] = src;
    }
  }
}

// K5: fused layer-1 (no-max softmax).  16-lane group per node, 4 nodes/wave.
// Chunk-of-4 edges: all 4 csr_src loads + 4 xl gathers issued before consumption
// (16 gathers in flight per wave).  Tail = clamped index + masked weight.
__global__ void k_node1f(const int* __restrict__ rowptr, const int* __restrict__ csr_src,
                         const float* __restrict__ xl, const float* __restrict__ xr,
                         const float* __restrict__ att, const float* __restrict__ b1,
                         const float* __restrict__ Wl2, const float* __restrict__ Wr2,
                         float* __restrict__ xl2, float* __restrict__ xr2, int N){
  int node = blockIdx.x*16 + (threadIdx.x>>4);
  int gl = threadIdx.x & 15;
  if(node >= N) return;
  int f4 = gl*4;
  float4 attv = *(const float4*)(att + f4);
  float4 xrv  = *(const float4*)(xr + (size_t)node*H + f4);
  int s = rowptr[node], t = rowptr[node+1];
  float d = 0.f;
  float ax=0.f, ay=0.f, az=0.f, aw=0.f;

  for(int k=s; k<t; k+=4){
    int tl = t - 1;
    int k1 = (k+1<t)? k+1 : tl;
    int k2 = (k+2<t)? k+2 : tl;
    int k3 = (k+3<t)? k+3 : tl;
    int s0 = csr_src[k],  s1 = csr_src[k1];
    int s2 = csr_src[k2], s3 = csr_src[k3];
    float4 x0 = *(const float4*)(xl + (size_t)s0*H + f4);
    float4 x1 = *(const float4*)(xl + (size_t)s1*H + f4);
    float4 x2 = *(const float4*)(xl + (size_t)s2*H + f4);
    float4 x3 = *(const float4*)(xl + (size_t)s3*H + f4);
    float msk1 = (k+1<t)? 1.f:0.f, msk2 = (k+2<t)? 1.f:0.f, msk3 = (k+3<t)? 1.f:0.f;
    #define PROC(xv, msk) { \
      float h0 = xv.x + xrv.x, h1 = xv.y + xrv.y, h2 = xv.z + xrv.z, h3 = xv.w + xrv.w; \
      float l0 = (h0>0.f)? h0 : NEG_SLOPE*h0; \
      float l1 = (h1>0.f)? h1 : NEG_SLOPE*h1; \
      float l2 = (h2>0.f)? h2 : NEG_SLOPE*h2; \
      float l3 = (h3>0.f)? h3 : NEG_SLOPE*h3; \
      float e = l0*attv.x + l1*attv.y + l2*attv.z + l3*attv.w; \
      _Pragma("unroll") \
      for(int o=1;o<16;o<<=1) e += __shfl_xor(e,o); \
      float w = msk * __expf(e); \
      d  += w; \
      ax += w*xv.x; ay += w*xv.y; az += w*xv.z; aw += w*xv.w; }
    PROC(x0, 1.f)
    PROC(x1, msk1)
    PROC(x2, msk2)
    PROC(x3, msk3)
    #undef PROC
  }

  float inv = 1.f/(d + EPS);
  float4 bv = *(const float4*)(b1 + f4);
  float h0 = ax*inv + bv.x, h1 = ay*inv + bv.y;
  float h2 = az*inv + bv.z, h3 = aw*inv + bv.w;
  // 4 projections within the 16-lane group
  float p0 = h0*Wl2[(f4+0)*FOUT+0] + h1*Wl2[(f4+1)*FOUT+0] + h2*Wl2[(f4+2)*FOUT+0] + h3*Wl2[(f4+3)*FOUT+0];
  float p1 = h0*Wl2[(f4+0)*FOUT+1] + h1*Wl2[(f4+1)*FOUT+1] + h2*Wl2[(f4+2)*FOUT+1] + h3*Wl2[(f4+3)*FOUT+1];
  float p2 = h0*Wr2[(f4+0)*FOUT+0] + h1*Wr2[(f4+1)*FOUT+0] + h2*Wr2[(f4+2)*FOUT+0] + h3*Wr2[(f4+3)*FOUT+0];
  float p3 = h0*Wr2[(f4+0)*FOUT+1] + h1*Wr2[(f4+1)*FOUT+1] + h2*Wr2[(f4+2)*FOUT+1] + h3*Wr2[(f4+3)*FOUT+1];
  #pragma unroll
  for(int o=1;o<16;o<<=1){
    p0 += __shfl_xor(p0,o); p1 += __shfl_xor(p1,o);
    p2 += __shfl_xor(p2,o); p3 += __shfl_xor(p3,o);
  }
  if(gl==0){
    *(float2*)(xl2 + node*2) = make_float2(p0,p1);
    *(float2*)(xr2 + node*2) = make_float2(p2,p3);
  }
}

// K7: layer-2 full conv, single pass (no-max), 16-lane group per node, 4 nodes/wave
__global__ void k_node2(const int* __restrict__ rowptr, const int* __restrict__ csr_src,
                        const float* __restrict__ xl2, const float* __restrict__ xr2,
                        const float* __restrict__ att2, const float* __restrict__ b2,
                        float* __restrict__ out, int N){
  int node = blockIdx.x*16 + (threadIdx.x>>4);
  int gl = threadIdx.x & 15;
  if(node >= N) return;
  int s = rowptr[node], t = rowptr[node+1];
  float2 xrv = *(const float2*)(xr2 + node*2);
  float a0 = att2[0], a1 = att2[1];
  float den=0.f, n0=0.f, n1=0.f;
  for(int k=s+gl; k<t; k+=16){
    int src = csr_src[k];
    float2 xs = *(const float2*)(xl2 + src*2);
    float h0 = xs.x + xrv.x, h1 = xs.y + xrv.y;
    float l0 = (h0>0.f)? h0 : NEG_SLOPE*h0;
    float l1 = (h1>0.f)? h1 : NEG_SLOPE*h1;
    float ex = __expf(l0*a0 + l1*a1);
    den += ex; n0 += ex*xs.x; n1 += ex*xs.y;
  }
  #pragma unroll
  for(int o=1;o<16;o<<=1){
    den += __shfl_xor(den,o);
    n0  += __shfl_xor(n0,o);
    n1  += __shfl_xor(n1,o);
  }
  if(gl==0){
    float inv = 1.f/(den + EPS);
    out[node*2+0] = n0*inv + b2[0];
    out[node*2+1] = n1*inv + b2[1];
  }
}

extern "C" void kernel_launch(void* const* d_in, const int* in_sizes, int n_in,
                              void* d_out, int out_size, void* d_ws, size_t ws_size,
                              hipStream_t stream){
  const float* x    = (const float*)d_in[0];
  const int*   ei   = (const int*)d_in[1];
  const float* Wl1  = (const float*)d_in[2];
  const float* Wr1  = (const float*)d_in[3];
  const float* att1 = (const float*)d_in[4];
  const float* b1   = (const float*)d_in[5];
  const float* Wl2  = (const float*)d_in[6];
  const float* Wr2  = (const float*)d_in[7];
  const float* att2 = (const float*)d_in[8];
  const float* b2   = (const float*)d_in[9];
  int N = in_sizes[0]/FIN;
  int E = in_sizes[1]/2;
  int Etot = E + N;
  int nscan = (N + SCAN_CHUNK - 1) / SCAN_CHUNK;   // 25 for N=50000 (<=64 supported)
  int nquad = (Etot + 3) / 4;                       // 4-edge packages

  char* w = (char*)d_ws;
  size_t off = 0;
  auto alloc = [&](size_t bytes)->void*{
    void* p = w + off;
    off = (off + bytes + 255) & ~(size_t)255;
    return p;
  };
  float* xl1     = (float*)alloc((size_t)N*H*4);
  float* xr1     = (float*)alloc((size_t)N*H*4);
  int*   csr_src = (int*)  alloc((size_t)Etot*4);
  int*   rank    = (int*)  alloc((size_t)Etot*4);
  int*   deg     = (int*)  alloc((size_t)N*4);
  int*   rowptr  = (int*)  alloc((size_t)(N+1)*4);
  int*   blocksum= (int*)  alloc((size_t)64*4);
  float* xl2     = (float*)alloc((size_t)N*2*4);
  float* xr2     = (float*)alloc((size_t)N*2*4);

  hipMemsetAsync(deg, 0, (size_t)N*4, stream);
  k_gemm1<<<(N+BM-1)/BM, 256, 0, stream>>>(x, Wl1, Wr1, xl1, xr1, N);
  k_degree<<<(nquad+255)/256,256,0,stream>>>(ei, E, Etot, deg, rank);
  k_scan_a<<<nscan,256,0,stream>>>(deg, N, rowptr, blocksum);
  k_scan_b<<<1,64,0,stream>>>(blocksum, nscan, rowptr, N);
  k_scan_c<<<(N+255)/256,256,0,stream>>>(rowptr, blocksum, N);
  k_fill<<<(nquad+255)/256,256,0,stream>>>(ei, E, Etot, rowptr, rank, csr_src);
  k_node1f<<<(N+15)/16, 256, 0, stream>>>(rowptr, csr_src, xl1, xr1, att1, b1, Wl2, Wr2, xl2, xr2, N);
  k_node2<<<(N+15)/16, 256, 0, stream>>>(rowptr, csr_src, xl2, xr2, att2, b2, (float*)d_out, N);
}

// Round 8
// 135.054 us; speedup vs baseline: 4.2307x; 1.0585x over previous
//
#include <hip/hip_runtime.h>
#include <math.h>

#define FIN 128
#define H 64
#define FOUT 2
#define NEG_SLOPE 0.2f
#define EPS 1e-16f

#define BM 64
#define BK 32
#define SCAN_CHUNK 2048   // elements per scan_a block (256 thr * 8)

// K1: [N,128] @ [128, 64|64] -> xl, xr.  LDS-tiled, 4x8 register micro-tile.
// BM=64 -> 782 blocks (~3/CU) so occupancy hides LDS/barrier latency.
__global__ __launch_bounds__(256) void k_gemm1(
    const float* __restrict__ x, const float* __restrict__ Wl,
    const float* __restrict__ Wr, float* __restrict__ xl,
    float* __restrict__ xr, int N){
  __shared__ float xsT[BK][BM+4];   // [kk][row] transposed, 8.7 KB
  __shared__ float ws[BK][128];     // [kk][col], col<64 Wl else Wr, 16 KB
  int tid = threadIdx.x;
  int rowbase = blockIdx.x*BM;
  int tc = tid & 15, tr = tid >> 4;    // tr in [0,16)
  int r0 = tr*4, c0 = tc*4;
  float acc[4][8];
  #pragma unroll
  for(int i=0;i<4;i++)
    #pragma unroll
    for(int j=0;j<8;j++) acc[i][j]=0.f;

  int lrow = tid >> 2;            // 0..63 (x stage row)
  int lk8  = (tid & 3) * 8;       // k-offset 0,8,16,24
  int wkk  = tid >> 3;            // 0..31 (W stage row)
  int wfq  = tid & 7;             // 0..7

  for(int k0=0; k0<FIN; k0+=BK){
    __syncthreads();
    // stage x tile (transposed)
    {
      int grow = rowbase + lrow;
      float4 v0 = make_float4(0,0,0,0), v1 = make_float4(0,0,0,0);
      if(grow < N){
        v0 = *(const float4*)(x + (size_t)grow*FIN + k0 + lk8);
        v1 = *(const float4*)(x + (size_t)grow*FIN + k0 + lk8 + 4);
      }
      xsT[lk8+0][lrow]=v0.x; xsT[lk8+1][lrow]=v0.y; xsT[lk8+2][lrow]=v0.z; xsT[lk8+3][lrow]=v0.w;
      xsT[lk8+4][lrow]=v1.x; xsT[lk8+5][lrow]=v1.y; xsT[lk8+6][lrow]=v1.z; xsT[lk8+7][lrow]=v1.w;
    }
    // stage W tile
    #pragma unroll
    for(int i=0;i<4;i++){
      int c4 = (wfq + i*8)*4;
      const float* srcp = (c4 < 64) ? (Wl + (size_t)(k0+wkk)*H + c4)
                                    : (Wr + (size_t)(k0+wkk)*H + (c4-64));
      *(float4*)(&ws[wkk][c4]) = *(const float4*)srcp;
    }
    __syncthreads();
    #pragma unroll
    for(int kk=0; kk<BK; kk++){
      float4 av = *(float4*)(&xsT[kk][r0]);
      float4 b0 = *(float4*)(&ws[kk][c0]);        // Wl cols
      float4 b1 = *(float4*)(&ws[kk][64+c0]);     // Wr cols
      float a[4] = {av.x,av.y,av.z,av.w};
      float b[8] = {b0.x,b0.y,b0.z,b0.w,b1.x,b1.y,b1.z,b1.w};
      #pragma unroll
      for(int i=0;i<4;i++)
        #pragma unroll
        for(int j=0;j<8;j++)
          acc[i][j] += a[i]*b[j];
    }
  }
  #pragma unroll
  for(int i=0;i<4;i++){
    int row = rowbase + r0 + i;
    if(row < N){
      *(float4*)(xl + (size_t)row*H + c0) = make_float4(acc[i][0],acc[i][1],acc[i][2],acc[i][3]);
      *(float4*)(xr + (size_t)row*H + c0) = make_float4(acc[i][4],acc[i][5],acc[i][6],acc[i][7]);
    }
  }
}

// K2: degree count + per-edge rank (uses the atomic's return value; coalesced rank write)
__global__ void k_degree(const int* __restrict__ ei, int E, int Etot,
                         int* __restrict__ deg, int* __restrict__ rank){
  int i0 = (blockIdx.x*blockDim.x + threadIdx.x)*4;
  if(i0 >= Etot) return;
  if(i0 + 4 <= E && (E & 3) == 0){
    int4 d4 = *(const int4*)(ei + E + i0);
    int r0 = atomicAdd(&deg[d4.x],1);
    int r1 = atomicAdd(&deg[d4.y],1);
    int r2 = atomicAdd(&deg[d4.z],1);
    int r3 = atomicAdd(&deg[d4.w],1);
    *(int4*)(rank + i0) = make_int4(r0,r1,r2,r3);
  } else if(i0 >= E && i0 + 4 <= Etot){
    int v = i0 - E;
    int r0 = atomicAdd(&deg[v+0],1);
    int r1 = atomicAdd(&deg[v+1],1);
    int r2 = atomicAdd(&deg[v+2],1);
    int r3 = atomicAdd(&deg[v+3],1);
    *(int4*)(rank + i0) = make_int4(r0,r1,r2,r3);
  } else {
    #pragma unroll
    for(int q=0;q<4;q++){
      int i = i0+q; if(i>=Etot) break;
      int dst = (i<E) ? ei[E+i] : (i-E);
      rank[i] = atomicAdd(&deg[dst],1);
    }
  }
}

// K3a: per-block scan of deg (2048 elems/block), local-exclusive into rowptr, block totals
__global__ __launch_bounds__(256) void k_scan_a(const int* __restrict__ deg, int n,
                                                int* __restrict__ rowptr,
                                                int* __restrict__ blocksum){
  __shared__ int wsum[4];
  int tid = threadIdx.x, lane = tid & 63, wid = tid >> 6;
  int idx = blockIdx.x*SCAN_CHUNK + tid*8;
  int v[8];
  if(idx + 8 <= n){
    int4 a = *(const int4*)(deg + idx);
    int4 b = *(const int4*)(deg + idx + 4);
    v[0]=a.x;v[1]=a.y;v[2]=a.z;v[3]=a.w;v[4]=b.x;v[5]=b.y;v[6]=b.z;v[7]=b.w;
  } else {
    #pragma unroll
    for(int i=0;i<8;i++) v[i] = (idx+i<n)? deg[idx+i] : 0;
  }
  int pre[8]; int st=0;
  #pragma unroll
  for(int i=0;i<8;i++){ pre[i]=st; st+=v[i]; }
  int incl = st;
  #pragma unroll
  for(int o=1;o<64;o<<=1){ int u=__shfl_up(incl,o); if(lane>=o) incl+=u; }
  if(lane==63) wsum[wid]=incl;
  __syncthreads();
  if(tid==0){ int accu=0; for(int i=0;i<4;i++){ int t=wsum[i]; wsum[i]=accu; accu+=t; } }
  __syncthreads();
  int toff = wsum[wid] + incl - st;
  if(idx + 8 <= n){
    int4 o0 = make_int4(toff+pre[0],toff+pre[1],toff+pre[2],toff+pre[3]);
    int4 o1 = make_int4(toff+pre[4],toff+pre[5],toff+pre[6],toff+pre[7]);
    *(int4*)(rowptr+idx)=o0; *(int4*)(rowptr+idx+4)=o1;
  } else {
    #pragma unroll
    for(int i=0;i<8;i++) if(idx+i<n) rowptr[idx+i]=toff+pre[i];
  }
  if(tid==255) blocksum[blockIdx.x] = toff + st;
}

// K3b: exclusive scan of block sums (nb <= 64), total -> rowptr[n]
__global__ void k_scan_b(int* __restrict__ blocksum, int nb, int* __restrict__ rowptr, int n){
  int lane = threadIdx.x & 63;
  int v = (lane<nb)? blocksum[lane] : 0;
  int incl = v;
  #pragma unroll
  for(int o=1;o<64;o<<=1){ int u=__shfl_up(incl,o); if(lane>=o) incl+=u; }
  if(lane<nb) blocksum[lane] = incl - v;
  if(lane==63) rowptr[n] = incl;
}

// K3c: add block offsets
__global__ void k_scan_c(int* __restrict__ rowptr, const int* __restrict__ blocksum, int n){
  int i = blockIdx.x*blockDim.x + threadIdx.x;
  if(i<n) rowptr[i] += blocksum[i >> 11];  // SCAN_CHUNK = 2048
}

// K4: CSR fill — no atomics; p = rowptr[dst] + rank[i]; 4-wide MLP
__global__ void k_fill(const int* __restrict__ ei, int E, int Etot,
                       const int* __restrict__ rowptr,
                       const int* __restrict__ rank, int* __restrict__ csr_src){
  int i0 = (blockIdx.x*blockDim.x + threadIdx.x)*4;
  if(i0 >= Etot) return;
  if(i0 + 4 <= E && (E & 3) == 0){
    int4 s4 = *(const int4*)(ei + i0);
    int4 d4 = *(const int4*)(ei + E + i0);
    int4 r4 = *(const int4*)(rank + i0);
    csr_src[rowptr[d4.x] + r4.x] = s4.x;
    csr_src[rowptr[d4.y] + r4.y] = s4.y;
    csr_src[rowptr[d4.z] + r4.z] = s4.z;
    csr_src[rowptr[d4.w] + r4.w] = s4.w;
  } else if(i0 >= E && i0 + 4 <= Etot){
    int4 r4 = *(const int4*)(rank + i0);
    int v = i0 - E;
    csr_src[rowptr[v+0] + r4.x] = v+0;
    csr_src[rowptr[v+1] + r4.y] = v+1;
    csr_src[rowptr[v+2] + r4.z] = v+2;
    csr_src[rowptr[v+3] + r4.w] = v+3;
  } else {
    #pragma unroll
    for(int q=0;q<4;q++){
      int i = i0+q; if(i>=Etot) break;
      int src, dst;
      if(i<E){ src = ei[i]; dst = ei[E+i]; } else { src = i-E; dst = i-E; }
      csr_src[rowptr[dst] + rank[i]] = src;
    }
  }
}

// K5: fused layer-1 (no-max softmax).  16-lane group per node, 4 nodes/wave.
// Chunk-of-8 edges: all 8 csr_src loads + 8 xl gathers issued before consumption
// (40 gathers in flight per wave).  Tail = clamped index + masked weight.
__global__ void k_node1f(const int* __restrict__ rowptr, const int* __restrict__ csr_src,
                         const float* __restrict__ xl, const float* __restrict__ xr,
                         const float* __restrict__ att, const float* __restrict__ b1,
                         const float* __restrict__ Wl2, const float* __restrict__ Wr2,
                         float* __restrict__ xl2, float* __restrict__ xr2, int N){
  int node = blockIdx.x*16 + (threadIdx.x>>4);
  int gl = threadIdx.x & 15;
  if(node >= N) return;
  int f4 = gl*4;
  float4 attv = *(const float4*)(att + f4);
  float4 xrv  = *(const float4*)(xr + (size_t)node*H + f4);
  int s = rowptr[node], t = rowptr[node+1];
  float d = 0.f;
  float ax=0.f, ay=0.f, az=0.f, aw=0.f;

  for(int k=s; k<t; k+=8){
    int tl = t - 1;
    int ks[8]; float4 xv[8]; float msk[8];
    #pragma unroll
    for(int j=0;j<8;j++){
      int kj = k + j;
      ks[j] = (kj < t) ? kj : tl;
      msk[j] = (kj < t) ? 1.f : 0.f;
    }
    int ss[8];
    #pragma unroll
    for(int j=0;j<8;j++) ss[j] = csr_src[ks[j]];
    #pragma unroll
    for(int j=0;j<8;j++) xv[j] = *(const float4*)(xl + (size_t)ss[j]*H + f4);
    #pragma unroll
    for(int j=0;j<8;j++){
      float h0 = xv[j].x + xrv.x, h1 = xv[j].y + xrv.y;
      float h2 = xv[j].z + xrv.z, h3 = xv[j].w + xrv.w;
      float l0 = (h0>0.f)? h0 : NEG_SLOPE*h0;
      float l1 = (h1>0.f)? h1 : NEG_SLOPE*h1;
      float l2 = (h2>0.f)? h2 : NEG_SLOPE*h2;
      float l3 = (h3>0.f)? h3 : NEG_SLOPE*h3;
      float e = l0*attv.x + l1*attv.y + l2*attv.z + l3*attv.w;
      #pragma unroll
      for(int o=1;o<16;o<<=1) e += __shfl_xor(e,o);
      float w = msk[j] * __expf(e);
      d  += w;
      ax += w*xv[j].x; ay += w*xv[j].y; az += w*xv[j].z; aw += w*xv[j].w;
    }
  }

  float inv = 1.f/(d + EPS);
  float4 bv = *(const float4*)(b1 + f4);
  float h0 = ax*inv + bv.x, h1 = ay*inv + bv.y;
  float h2 = az*inv + bv.z, h3 = aw*inv + bv.w;
  // 4 projections within the 16-lane group
  float p0 = h0*Wl2[(f4+0)*FOUT+0] + h1*Wl2[(f4+1)*FOUT+0] + h2*Wl2[(f4+2)*FOUT+0] + h3*Wl2[(f4+3)*FOUT+0];
  float p1 = h0*Wl2[(f4+0)*FOUT+1] + h1*Wl2[(f4+1)*FOUT+1] + h2*Wl2[(f4+2)*FOUT+1] + h3*Wl2[(f4+3)*FOUT+1];
  float p2 = h0*Wr2[(f4+0)*FOUT+0] + h1*Wr2[(f4+1)*FOUT+0] + h2*Wr2[(f4+2)*FOUT+0] + h3*Wr2[(f4+3)*FOUT+0];
  float p3 = h0*Wr2[(f4+0)*FOUT+1] + h1*Wr2[(f4+1)*FOUT+1] + h2*Wr2[(f4+2)*FOUT+1] + h3*Wr2[(f4+3)*FOUT+1];
  #pragma unroll
  for(int o=1;o<16;o<<=1){
    p0 += __shfl_xor(p0,o); p1 += __shfl_xor(p1,o);
    p2 += __shfl_xor(p2,o); p3 += __shfl_xor(p3,o);
  }
  if(gl==0){
    *(float2*)(xl2 + node*2) = make_float2(p0,p1);
    *(float2*)(xr2 + node*2) = make_float2(p2,p3);
  }
}

// K7: layer-2 full conv, single pass (no-max), 16-lane group per node, 4 nodes/wave
__global__ void k_node2(const int* __restrict__ rowptr, const int* __restrict__ csr_src,
                        const float* __restrict__ xl2, const float* __restrict__ xr2,
                        const float* __restrict__ att2, const float* __restrict__ b2,
                        float* __restrict__ out, int N){
  int node = blockIdx.x*16 + (threadIdx.x>>4);
  int gl = threadIdx.x & 15;
  if(node >= N) return;
  int s = rowptr[node], t = rowptr[node+1];
  float2 xrv = *(const float2*)(xr2 + node*2);
  float a0 = att2[0], a1 = att2[1];
  float den=0.f, n0=0.f, n1=0.f;
  for(int k=s+gl; k<t; k+=16){
    int src = csr_src[k];
    float2 xs = *(const float2*)(xl2 + src*2);
    float h0 = xs.x + xrv.x, h1 = xs.y + xrv.y;
    float l0 = (h0>0.f)? h0 : NEG_SLOPE*h0;
    float l1 = (h1>0.f)? h1 : NEG_SLOPE*h1;
    float ex = __expf(l0*a0 + l1*a1);
    den += ex; n0 += ex*xs.x; n1 += ex*xs.y;
  }
  #pragma unroll
  for(int o=1;o<16;o<<=1){
    den += __shfl_xor(den,o);
    n0  += __shfl_xor(n0,o);
    n1  += __shfl_xor(n1,o);
  }
  if(gl==0){
    float inv = 1.f/(den + EPS);
    out[node*2+0] = n0*inv + b2[0];
    out[node*2+1] = n1*inv + b2[1];
  }
}

extern "C" void kernel_launch(void* const* d_in, const int* in_sizes, int n_in,
                              void* d_out, int out_size, void* d_ws, size_t ws_size,
                              hipStream_t stream){
  const float* x    = (const float*)d_in[0];
  const int*   ei   = (const int*)d_in[1];
  const float* Wl1  = (const float*)d_in[2];
  const float* Wr1  = (const float*)d_in[3];
  const float* att1 = (const float*)d_in[4];
  const float* b1   = (const float*)d_in[5];
  const float* Wl2  = (const float*)d_in[6];
  const float* Wr2  = (const float*)d_in[7];
  const float* att2 = (const float*)d_in[8];
  const float* b2   = (const float*)d_in[9];
  int N = in_sizes[0]/FIN;
  int E = in_sizes[1]/2;
  int Etot = E + N;
  int nscan = (N + SCAN_CHUNK - 1) / SCAN_CHUNK;   // 25 for N=50000 (<=64 supported)
  int nquad = (Etot + 3) / 4;                       // 4-edge packages

  char* w = (char*)d_ws;
  size_t off = 0;
  auto alloc = [&](size_t bytes)->void*{
    void* p = w + off;
    off = (off + bytes + 255) & ~(size_t)255;
    return p;
  };
  float* xl1     = (float*)alloc((size_t)N*H*4);
  float* xr1     = (float*)alloc((size_t)N*H*4);
  int*   csr_src = (int*)  alloc((size_t)Etot*4);
  int*   rank    = (int*)  alloc((size_t)Etot*4);
  int*   deg     = (int*)  alloc((size_t)N*4);
  int*   rowptr  = (int*)  alloc((size_t)(N+1)*4);
  int*   blocksum= (int*)  alloc((size_t)64*4);
  float* xl2     = (float*)alloc((size_t)N*2*4);
  float* xr2     = (float*)alloc((size_t)N*2*4);

  hipMemsetAsync(deg, 0, (size_t)N*4, stream);
  k_gemm1<<<(N+BM-1)/BM, 256, 0, stream>>>(x, Wl1, Wr1, xl1, xr1, N);
  k_degree<<<(nquad+255)/256,256,0,stream>>>(ei, E, Etot, deg, rank);
  k_scan_a<<<nscan,256,0,stream>>>(deg, N, rowptr, blocksum);
  k_scan_b<<<1,64,0,stream>>>(blocksum, nscan, rowptr, N);
  k_scan_c<<<(N+255)/256,256,0,stream>>>(rowptr, blocksum, N);
  k_fill<<<(nquad+255)/256,256,0,stream>>>(ei, E, Etot, rowptr, rank, csr_src);
  k_node1f<<<(N+15)/16, 256, 0, stream>>>(rowptr, csr_src, xl1, xr1, att1, b1, Wl2, Wr2, xl2, xr2, N);
  k_node2<<<(N+15)/16, 256, 0, stream>>>(rowptr, csr_src, xl2, xr2, att2, b2, (float*)d_out, N);
}